// Round 14
// baseline (97.691 us; speedup 1.0000x reference)
//
#include <hip/hip_runtime.h>
#include <math.h>

#define B_DIM 2
#define C_DIM 256
#define N_TOK 4096      // 16*16*16
#define HEADS 4
#define HD 64
#define GROUPS 8
#define CPG (C_DIM / GROUPS)   // 32
#define EPS 1e-5f
#define PSB 72          // padded bf16 LDS row stride (Xt staging)
#define QK_SCALE 0.180336880f  // 0.125 * log2(e), folded into Q
#define NKT (N_TOK / 64)       // 64 key tiles total
#define QBLK 256               // queries per attention block (8 waves x 2 frags x 16 q)
#define NQKVW (3 * C_DIM * C_DIM)   // 196608 qkv_w elems
#define NPROJW (C_DIM * C_DIM)      // 65536 proj_w elems

typedef __bf16 bf16x8 __attribute__((ext_vector_type(8)));
typedef float  f32x4  __attribute__((ext_vector_type(4)));
typedef unsigned short u16x4v __attribute__((ext_vector_type(4)));
typedef unsigned short u16x8v __attribute__((ext_vector_type(8)));

__device__ __forceinline__ unsigned short f2bf(float f) {
    return __builtin_bit_cast(unsigned short, (__bf16)f);
}
__device__ __forceinline__ float bf2f(unsigned short u) {
    return (float)__builtin_bit_cast(__bf16, u);
}
// raw v_exp_f32 (2^x); inputs bounded so no OCML fixup needed
__device__ __forceinline__ float exp2_fast(float x) { return __builtin_amdgcn_exp2f(x); }

// async global->LDS, 16B per lane, wave-uniform LDS base (linear dest)
__device__ __forceinline__ void gload16(const unsigned short* g, unsigned short* l) {
    __builtin_amdgcn_global_load_lds(
        (const __attribute__((address_space(1))) unsigned int*)g,
        (__attribute__((address_space(3))) unsigned int*)l, 16, 0, 0);
}

// K-staging row permutation: [b5 b4 b3 b2 b1 b0] -> [b5 b3 b2 b4 b1 b0].
// Makes the S^T output registers exactly the PV B-fragment.
__device__ __forceinline__ int kperm(int r) {
    return (r & 0x23) | ((r & 0x0C) << 1) | ((r & 0x10) >> 2);
}

// ---------------------------------------------------------------------------
// Kernel 1: GroupNorm partial sums (1024 blocks) + weight f32->bf16 convert
// tail (262144 = 1024*256 elems, one per thread, coalesced).
__global__ __launch_bounds__(256) void gn_part_kernel(const float* __restrict__ x,
                                                      const float* __restrict__ qkv_w,
                                                      const float* __restrict__ proj_w,
                                                      float* __restrict__ partials,
                                                      unsigned short* __restrict__ wbf) {
    const int bg = blockIdx.x >> 6, ch = blockIdx.x & 63;
    const float4* p = (const float4*)(x + (size_t)bg * CPG * N_TOK) + ch * 512;
    float s = 0.f, ss = 0.f;
#pragma unroll
    for (int r = 0; r < 2; ++r) {
        float4 v = p[threadIdx.x + (r << 8)];
        s  += v.x + v.y + v.z + v.w;
        ss += v.x * v.x + v.y * v.y + v.z * v.z + v.w * v.w;
    }
#pragma unroll
    for (int off = 32; off > 0; off >>= 1) {
        s  += __shfl_down(s, off);
        ss += __shfl_down(ss, off);
    }
    __shared__ float ls[4], lss[4];
    const int lane = threadIdx.x & 63, wid = threadIdx.x >> 6;
    if (lane == 0) { ls[wid] = s; lss[wid] = ss; }

    // weight convert tail (no sync needed; independent outputs)
    const int widx = blockIdx.x * 256 + threadIdx.x;
    float wv = (widx < NQKVW) ? qkv_w[widx] : proj_w[widx - NQKVW];
    wbf[widx] = f2bf(wv);

    __syncthreads();
    if (threadIdx.x == 0) {
        partials[blockIdx.x * 2 + 0] = ls[0] + ls[1] + ls[2] + ls[3];
        partials[blockIdx.x * 2 + 1] = lss[0] + lss[1] + lss[2] + lss[3];
    }
}

// ---------------------------------------------------------------------------
// Kernel 2: fused GroupNorm finalize + apply + QKV GEMM, bf16 MFMA.
// 64x64 tile, 256 threads. Ws staged via global_load_lds from pre-converted
// bf16 weights (XOR-swizzled source, linear LDS dest); Xt reg-staged.
__global__ __launch_bounds__(256) void qkv_gemm_kernel(
    const float* __restrict__ x, const float* __restrict__ partials,
    const float* __restrict__ norm_w, const float* __restrict__ norm_b,
    const unsigned short* __restrict__ wqbf, const float* __restrict__ qkv_b,
    unsigned short* __restrict__ qkvb) {
    __shared__ unsigned short Ws[64][64];   // [o][c] bf16, col-swizzled
    __shared__ unsigned short Xt[64][PSB];  // [n][c] bf16 (transposed xn)
    __shared__ float stat_s[GROUPS][2];
    const int n0 = blockIdx.x * 64;
    const int o0 = blockIdx.y * 64;
    const int b  = blockIdx.z;
    const int tid = threadIdx.x;
    const int lane = tid & 63, w = tid >> 6;
    const int lo = lane & 15, hi = lane >> 4;
    const int srow8 = lane >> 3, sblk = lane & 7;
    const int c16s = (sblk ^ srow8) * 8;    // swizzled source chunk (elements)
    int rcol[2];
#pragma unroll
    for (int c = 0; c < 2; ++c) rcol[c] = (((c * 4 + hi) ^ (lo & 7)) << 3);

    // finalize GroupNorm stats from partials (each block, redundantly; cheap)
    {
        const int g = tid >> 5, sub = tid & 31;
        const float* pp = partials + (((size_t)b * GROUPS + g) * 64 + sub * 2) * 2;
        float4 v = *(const float4*)pp;
        float s = v.x + v.z, ss = v.y + v.w;
#pragma unroll
        for (int off = 16; off > 0; off >>= 1) {
            s  += __shfl_down(s, off, 32);
            ss += __shfl_down(ss, off, 32);
        }
        if (sub == 0) {
            const float inv = 1.f / (float)(CPG * N_TOK);
            float mean = s * inv;
            float var  = ss * inv - mean * mean;
            stat_s[g][0] = mean;
            stat_s[g][1] = rsqrtf(var + EPS);
        }
        __syncthreads();
    }

    f32x4 acc[4] = {};
    for (int k0 = 0; k0 < C_DIM; k0 += 64) {
#pragma unroll
        for (int i = 0; i < 2; ++i) {
            int row = i * 32 + w * 8 + srow8;
            gload16(wqbf + (size_t)(o0 + row) * C_DIM + k0 + c16s, &Ws[i * 32 + w * 8][0]);
        }
#pragma unroll
        for (int r = 0; r < 4; ++r) {
            int idx = tid + (r << 8);
            int crow = idx >> 4, col4 = (idx & 15) << 2;
            int c = k0 + crow;
            int g = c >> 5;
            float ww = norm_w[c] * stat_s[g][1];
            float bb = norm_b[c] - stat_s[g][0] * ww;
            float4 v = *(const float4*)(x + ((size_t)b * C_DIM + c) * N_TOK + n0 + col4);
            Xt[col4 + 0][crow] = f2bf(v.x * ww + bb);
            Xt[col4 + 1][crow] = f2bf(v.y * ww + bb);
            Xt[col4 + 2][crow] = f2bf(v.z * ww + bb);
            Xt[col4 + 3][crow] = f2bf(v.w * ww + bb);
        }
        __syncthreads();   // drains DMA (vmcnt) + ds_writes (lgkm)
#pragma unroll
        for (int ck = 0; ck < 2; ++ck) {
            bf16x8 aw = *(const bf16x8*)&Ws[w * 16 + lo][rcol[ck]];
#pragma unroll
            for (int nb = 0; nb < 4; ++nb)
                acc[nb] = __builtin_amdgcn_mfma_f32_16x16x32_bf16(
                    aw, *(const bf16x8*)&Xt[nb * 16 + lo][ck * 32 + hi * 8], acc[nb], 0, 0, 0);
        }
        __syncthreads();
    }

    const int sidx = o0 >> 8;           // 0=q, 1=k, 2=v
    const int head = (o0 >> 6) & 3;
    const int od = w * 16 + hi * 4;     // d within head (+i)
    float bias[4];
#pragma unroll
    for (int i = 0; i < 4; ++i) bias[i] = qkv_b[o0 + od + i];
    const size_t plane = (size_t)N_TOK * HD;

    if (sidx < 2) {
        const float sc = (sidx == 0) ? QK_SCALE : 1.0f;
        unsigned short* base = qkvb + ((size_t)(sidx * B_DIM + b) * HEADS + head) * plane;
#pragma unroll
        for (int nb = 0; nb < 4; ++nb) {
            int n = n0 + nb * 16 + lo;
            u16x4v o;
#pragma unroll
            for (int i = 0; i < 4; ++i) o[i] = f2bf((acc[nb][i] + bias[i]) * sc);
            *(u16x4v*)(base + (size_t)n * HD + od) = o;
        }
    } else {
        unsigned short* base = qkvb + (size_t)2 * B_DIM * HEADS * plane
                             + ((size_t)b * HEADS + head) * plane;
#pragma unroll
        for (int nb = 0; nb < 4; ++nb)
#pragma unroll
            for (int i = 0; i < 4; ++i)
                base[(size_t)(od + i) * N_TOK + n0 + nb * 16 + lo] = f2bf(acc[nb][i] + bias[i]);
    }
}

// ---------------------------------------------------------------------------
// Kernel 3: bf16 MFMA flash attention (round-10 structure), K-split templated.
// KS = key-split factor; KSH = log2(KS). blockIdx: bits[2:0]=bh, [KSH+2:3]=ks.
template <int KS, int KSH>
__global__ __launch_bounds__(512, 4) void attn_kernel(const unsigned short* __restrict__ qkvb,
                                                      unsigned short* __restrict__ obuf,
                                                      float* __restrict__ rbuf) {
    const int bh = blockIdx.x & 7;            // b*HEADS + head
    const int ks = (blockIdx.x >> 3) & (KS - 1);
    const int q0 = (blockIdx.x >> (3 + KSH)) * QBLK;
    const size_t plane = (size_t)N_TOK * HD;
    const unsigned short* Qg  = qkvb + (size_t)bh * plane;
    const unsigned short* Kg  = qkvb + (size_t)(B_DIM * HEADS + bh) * plane;
    const unsigned short* Vtg = qkvb + (size_t)2 * B_DIM * HEADS * plane + (size_t)bh * plane;

    __shared__ unsigned short Ks_[2][64][64];  // [buf][perm key row][d] (col-swizzled)
    __shared__ unsigned short Vt[2][64][64];   // [buf][d][key]          (col-swizzled)

    const int tid  = threadIdx.x;
    const int lane = tid & 63;
    const int wid  = tid >> 6;                // 0..7
    const int lo   = lane & 15;
    const int hi   = lane >> 4;

    // Q fragments: frag f covers q = q0 + wid*32 + f*16 + lo, d-chunks c*32+hi*8
    bf16x8 qf[2][2];
#pragma unroll
    for (int f = 0; f < 2; ++f)
#pragma unroll
        for (int c = 0; c < 2; ++c)
            qf[f][c] = *(const bf16x8*)(Qg + (size_t)(q0 + wid * 32 + f * 16 + lo) * HD
                                            + c * 32 + hi * 8);

    const int srow = tid >> 3, sblk = tid & 7;
    const int c16s = (sblk ^ (srow & 7)) * 8;
    const int krow = kperm(srow);
    int rcol[2];
#pragma unroll
    for (int c = 0; c < 2; ++c) rcol[c] = (((c * 4 + hi) ^ (lo & 7)) << 3);

#define STAGE_KV(bufi, kbase)                                                          \
    do {                                                                               \
        gload16(Kg + (size_t)((kbase) + krow) * HD + c16s, &Ks_[bufi][wid * 8][0]);    \
        gload16(Vtg + (size_t)srow * N_TOK + (kbase) + c16s, &Vt[bufi][wid * 8][0]);   \
    } while (0)

    const int kt0 = ks * (NKT / KS), ktE = kt0 + NKT / KS;

    f32x4 acc[2][4] = {};   // acc[f][db][i] = O^T[d=db*16+hi*4+i][q of frag f]
    float m[2] = {-1e30f, -1e30f}, l[2] = {0.f, 0.f};

    STAGE_KV(0, kt0 * 64);
    __syncthreads();   // drains the DMA (vmcnt 0) + barrier

    for (int kt = kt0; kt < ktE; ++kt) {
        const int cur = kt & 1;
        if (kt + 1 < ktE) STAGE_KV(cur ^ 1, (kt + 1) * 64);

        // S^T = K Q^T for BOTH frags; each K fragment read once, used twice.
        f32x4 s4[2][4] = {};
        __builtin_amdgcn_s_setprio(1);
#pragma unroll
        for (int kb = 0; kb < 4; ++kb)
#pragma unroll
            for (int c = 0; c < 2; ++c) {
                bf16x8 kf = *(const bf16x8*)&Ks_[cur][kb * 16 + lo][rcol[c]];
                s4[0][kb] = __builtin_amdgcn_mfma_f32_16x16x32_bf16(kf, qf[0][c], s4[0][kb], 0, 0, 0);
                s4[1][kb] = __builtin_amdgcn_mfma_f32_16x16x32_bf16(kf, qf[1][c], s4[1][kb], 0, 0, 0);
            }
        __builtin_amdgcn_s_setprio(0);

        // softmax per frag (lane-local; cross-lane only in rare rescale branch)
        bf16x8 pf[2][2];
#pragma unroll
        for (int f = 0; f < 2; ++f) {
            float r0 = fmaxf(fmaxf(fmaxf(s4[f][0][0], s4[f][0][1]), s4[f][0][2]), s4[f][0][3]);
            float r1 = fmaxf(fmaxf(fmaxf(s4[f][1][0], s4[f][1][1]), s4[f][1][2]), s4[f][1][3]);
            float r2 = fmaxf(fmaxf(fmaxf(s4[f][2][0], s4[f][2][1]), s4[f][2][2]), s4[f][2][3]);
            float r3 = fmaxf(fmaxf(fmaxf(s4[f][3][0], s4[f][3][1]), s4[f][3][2]), s4[f][3][3]);
            float rm = fmaxf(fmaxf(fmaxf(r0, r1), r2), r3);

            // defer-max (T13) with LOCAL max check
            if (__any(rm > m[f] + 8.0f)) {
                float rmx = rm;
                rmx = fmaxf(rmx, __shfl_xor(rmx, 16));
                rmx = fmaxf(rmx, __shfl_xor(rmx, 32));
                const float mn = fmaxf(m[f], rmx);
                const float fi = exp2_fast(m[f] - mn);
                m[f] = mn;
                l[f] *= fi;
#pragma unroll
                for (int db = 0; db < 4; ++db)
#pragma unroll
                    for (int i = 0; i < 4; ++i) acc[f][db][i] *= fi;
            }

            float p[4][4];
            float ps = 0.f;
#pragma unroll
            for (int kb = 0; kb < 4; ++kb)
#pragma unroll
                for (int i = 0; i < 4; ++i) {
                    p[kb][i] = exp2_fast(s4[f][kb][i] - m[f]);
                    ps += p[kb][i];
                }
            l[f] += ps;

            // pack P into PV B-fragment: pf[f][c][j] = p[2c + (j>>2)][j&3]
#pragma unroll
            for (int c = 0; c < 2; ++c)
#pragma unroll
                for (int j = 0; j < 8; ++j) pf[f][c][j] = (__bf16)p[2 * c + (j >> 2)][j & 3];
        }

        // O^T += V^T P^T for BOTH frags; each V fragment read once, used twice.
        __builtin_amdgcn_s_setprio(1);
#pragma unroll
        for (int db = 0; db < 4; ++db)
#pragma unroll
            for (int c = 0; c < 2; ++c) {
                bf16x8 vf = *(const bf16x8*)&Vt[cur][db * 16 + lo][rcol[c]];
                acc[0][db] = __builtin_amdgcn_mfma_f32_16x16x32_bf16(vf, pf[0][c], acc[0][db], 0, 0, 0);
                acc[1][db] = __builtin_amdgcn_mfma_f32_16x16x32_bf16(vf, pf[1][c], acc[1][db], 0, 0, 0);
            }
        __builtin_amdgcn_s_setprio(0);

        __syncthreads();
    }
#undef STAGE_KV

    // epilogue per frag: normalized bf16 partial O + log-sum-exp r
#pragma unroll
    for (int f = 0; f < 2; ++f) {
        float l1 = l[f] + __shfl_xor(l[f], 16);
        float lt = l1 + __shfl_xor(l1, 32);
        const float inv = 1.f / lt;
        const int n = q0 + wid * 32 + f * 16 + lo;
        unsigned short* ob = obuf + ((size_t)(ks * 8 + bh) * N_TOK + n) * HD;
#pragma unroll
        for (int db = 0; db < 4; ++db) {
            u16x4v o;
#pragma unroll
            for (int i = 0; i < 4; ++i) o[i] = f2bf(acc[f][db][i] * inv);
            *(u16x4v*)(ob + db * 16 + hi * 4) = o;
        }
        if (hi == 0)
            rbuf[(size_t)(ks * 8 + bh) * N_TOK + n] = m[f] + __builtin_amdgcn_logf(lt);
    }
}

// ---------------------------------------------------------------------------
// Kernel 3b: combine the KS K-split parts -> hT [b][n][c] bf16.
template <int KS>
__global__ __launch_bounds__(256) void attn_combine_kernel(
    const unsigned short* __restrict__ obuf, const float* __restrict__ rbuf,
    unsigned short* __restrict__ hT) {
    const int idx = blockIdx.x * 256 + threadIdx.x;
    const int dq  = (idx & 3) * 16;
    const int bhn = idx >> 2;                  // bh*N_TOK + n
    const int n   = bhn & (N_TOK - 1);
    const int bh  = bhn >> 12;
    float r[KS], M = -1e30f;
#pragma unroll
    for (int k = 0; k < KS; ++k) {
        r[k] = rbuf[(size_t)(k * 8 + bh) * N_TOK + n];
        M = fmaxf(M, r[k]);
    }
    float w[KS], tot = 0.f;
#pragma unroll
    for (int k = 0; k < KS; ++k) { w[k] = exp2_fast(r[k] - M); tot += w[k]; }
    const float inv = 1.f / tot;
    const int b = bh >> 2, head = bh & 3;
    unsigned short* dst = hT + ((size_t)b * N_TOK + n) * C_DIM + head * HD + dq;
#pragma unroll
    for (int c = 0; c < 2; ++c) {
        float a[8] = {};
#pragma unroll
        for (int k = 0; k < KS; ++k) {
            u16x8v v = *(const u16x8v*)(obuf + ((size_t)(k * 8 + bh) * N_TOK + n) * HD + dq + c * 8);
#pragma unroll
            for (int j = 0; j < 8; ++j) a[j] += w[k] * bf2f(v[j]);
        }
        u16x8v o;
#pragma unroll
        for (int j = 0; j < 8; ++j) o[j] = f2bf(a[j] * inv);
        *(u16x8v*)(dst + c * 8) = o;
    }
}

// ---------------------------------------------------------------------------
// Kernel 4: output projection + bias + residual, bf16 MFMA. Pure m97-style
// GEMM: BOTH operands staged via global_load_lds (bf16 weights + hT).
__global__ __launch_bounds__(256) void proj_kernel(
    const unsigned short* __restrict__ hT, const unsigned short* __restrict__ wpbf,
    const float* __restrict__ proj_b, const float* __restrict__ x,
    float* __restrict__ out) {
    __shared__ unsigned short Ws[64][64];  // [o][c] bf16, col-swizzled
    __shared__ unsigned short Hs[64][64];  // [n][c] bf16, col-swizzled
    const int n0 = blockIdx.x * 64;
    const int o0 = blockIdx.y * 64;
    const int b  = blockIdx.z;
    const int tid = threadIdx.x;
    const int lane = tid & 63, w = tid >> 6;
    const int lo = lane & 15, hi = lane >> 4;
    const int srow8 = lane >> 3, sblk = lane & 7;
    const int c16s = (sblk ^ srow8) * 8;
    int rcol[2];
#pragma unroll
    for (int c = 0; c < 2; ++c) rcol[c] = (((c * 4 + hi) ^ (lo & 7)) << 3);

    f32x4 acc[4] = {};
    for (int k0 = 0; k0 < C_DIM; k0 += 64) {
#pragma unroll
        for (int i = 0; i < 2; ++i) {
            int row = i * 32 + w * 8 + srow8;
            gload16(wpbf + (size_t)(o0 + row) * C_DIM + k0 + c16s, &Ws[i * 32 + w * 8][0]);
            gload16(hT + ((size_t)b * N_TOK + n0 + row) * C_DIM + k0 + c16s,
                    &Hs[i * 32 + w * 8][0]);
        }
        __syncthreads();   // drains DMA
#pragma unroll
        for (int ck = 0; ck < 2; ++ck) {
            bf16x8 aw = *(const bf16x8*)&Ws[w * 16 + lo][rcol[ck]];
#pragma unroll
            for (int nb = 0; nb < 4; ++nb)
                acc[nb] = __builtin_amdgcn_mfma_f32_16x16x32_bf16(
                    aw, *(const bf16x8*)&Hs[nb * 16 + lo][rcol[ck]], acc[nb], 0, 0, 0);
        }
        __syncthreads();
    }

#pragma unroll
    for (int nb = 0; nb < 4; ++nb) {
#pragma unroll
        for (int i = 0; i < 4; ++i) {
            int o = o0 + w * 16 + hi * 4 + i;
            size_t addr = ((size_t)b * C_DIM + o) * N_TOK + n0 + nb * 16 + lo;
            out[addr] = acc[nb][i] + proj_b[o] + x[addr];
        }
    }
}

// ---------------------------------------------------------------------------
extern "C" void kernel_launch(void* const* d_in, const int* in_sizes, int n_in,
                              void* d_out, int out_size, void* d_ws, size_t ws_size,
                              hipStream_t stream) {
    const float* x      = (const float*)d_in[0];
    const float* norm_w = (const float*)d_in[1];
    const float* norm_b = (const float*)d_in[2];
    const float* qkv_w  = (const float*)d_in[3];
    const float* qkv_b  = (const float*)d_in[4];
    const float* proj_w = (const float*)d_in[5];
    const float* proj_b = (const float*)d_in[6];
    float* out = (float*)d_out;

    // ws layout: partials f32[2048] | wbf u16[262144] | qkvb bf16 (12.6MB)
    //   | obuf bf16 [KS*8][N][HD] | rbuf f32 [KS*8][N]
    // KS=8 needs ~45.5MiB; falls back to KS=4 (~30.4MB, proven) if ws is small.
    float* partials = (float*)d_ws;
    unsigned short* wbf = (unsigned short*)(partials + 2048);
    unsigned short* qkvb = wbf + (NQKVW + NPROJW);
    unsigned short* hT = qkvb;  // q-plane reuse (4MB; attn done before combine)
    unsigned short* obuf = qkvb + (size_t)3 * B_DIM * HEADS * N_TOK * HD;
    const unsigned short* wqbf = wbf;
    const unsigned short* wpbf = wbf + NQKVW;

    const size_t base_bytes = 2048 * 4 + (size_t)(NQKVW + NPROJW) * 2
                            + (size_t)3 * B_DIM * HEADS * N_TOK * HD * 2;
    const size_t per_ks = (size_t)B_DIM * HEADS * N_TOK * HD * 2   // obuf plane set
                        + (size_t)B_DIM * HEADS * N_TOK * 4;       // rbuf plane set
    const bool use8 = ws_size >= base_bytes + 8 * per_ks;

    gn_part_kernel<<<B_DIM * GROUPS * 64, 256, 0, stream>>>(x, qkv_w, proj_w, partials, wbf);
    qkv_gemm_kernel<<<dim3(N_TOK / 64, 3 * C_DIM / 64, B_DIM), 256, 0, stream>>>(
        x, partials, norm_w, norm_b, wqbf, qkv_b, qkvb);

    if (use8) {
        float* rbuf = (float*)(obuf + (size_t)8 * B_DIM * HEADS * N_TOK * HD);
        attn_kernel<8, 3><<<(N_TOK / QBLK) * B_DIM * HEADS * 8, 512, 0, stream>>>(
            qkvb, obuf, rbuf);
        attn_combine_kernel<8><<<B_DIM * HEADS * N_TOK * 4 / 256, 256, 0, stream>>>(
            obuf, rbuf, hT);
    } else {
        float* rbuf = (float*)(obuf + (size_t)4 * B_DIM * HEADS * N_TOK * HD);
        attn_kernel<4, 2><<<(N_TOK / QBLK) * B_DIM * HEADS * 4, 512, 0, stream>>>(
            qkvb, obuf, rbuf);
        attn_combine_kernel<4><<<B_DIM * HEADS * N_TOK * 4 / 256, 256, 0, stream>>>(
            obuf, rbuf, hT);
    }
    proj_kernel<<<dim3(N_TOK / 64, C_DIM / 64, B_DIM), 256, 0, stream>>>(
        hT, wpbf, proj_b, x, out);
}

// Round 15
// 87.839 us; speedup vs baseline: 1.1122x; 1.1122x over previous
//
#include <hip/hip_runtime.h>
#include <math.h>

#define B_DIM 2
#define C_DIM 256
#define N_TOK 4096      // 16*16*16
#define HEADS 4
#define HD 64
#define GROUPS 8
#define CPG (C_DIM / GROUPS)   // 32
#define EPS 1e-5f
#define PSB 72          // padded bf16 LDS row stride (reg-staged tiles)
#define QK_SCALE 0.180336880f  // 0.125 * log2(e), folded into Q
#define KSPLIT 4
#define NKT (N_TOK / 64)       // 64 key tiles total
#define QBLK 256               // queries per attention block (8 waves x 2 frags x 16 q)
#define NQKVW (3 * C_DIM * C_DIM)   // 196608 qkv_w elems
#define NPROJW (C_DIM * C_DIM)      // 65536 proj_w elems

typedef __bf16 bf16x8 __attribute__((ext_vector_type(8)));
typedef float  f32x4  __attribute__((ext_vector_type(4)));
typedef unsigned short u16x4v __attribute__((ext_vector_type(4)));
typedef unsigned short u16x8v __attribute__((ext_vector_type(8)));

__device__ __forceinline__ unsigned short f2bf(float f) {
    return __builtin_bit_cast(unsigned short, (__bf16)f);
}
__device__ __forceinline__ float bf2f(unsigned short u) {
    return (float)__builtin_bit_cast(__bf16, u);
}
// raw v_exp_f32 (2^x); inputs bounded so no OCML fixup needed
__device__ __forceinline__ float exp2_fast(float x) { return __builtin_amdgcn_exp2f(x); }

// async global->LDS, 16B per lane, wave-uniform LDS base (linear dest)
__device__ __forceinline__ void gload16(const unsigned short* g, unsigned short* l) {
    __builtin_amdgcn_global_load_lds(
        (const __attribute__((address_space(1))) unsigned int*)g,
        (__attribute__((address_space(3))) unsigned int*)l, 16, 0, 0);
}

// K-staging row permutation: [b5 b4 b3 b2 b1 b0] -> [b5 b3 b2 b4 b1 b0].
// Makes the S^T output registers exactly the PV B-fragment.
__device__ __forceinline__ int kperm(int r) {
    return (r & 0x23) | ((r & 0x0C) << 1) | ((r & 0x10) >> 2);
}

// ---------------------------------------------------------------------------
// Kernel 1: GroupNorm partial sums (1024 blocks) + weight f32->bf16 convert
// tail (262144 = 1024*256 elems, one per thread, coalesced).
__global__ __launch_bounds__(256) void gn_part_kernel(const float* __restrict__ x,
                                                      const float* __restrict__ qkv_w,
                                                      const float* __restrict__ proj_w,
                                                      float* __restrict__ partials,
                                                      unsigned short* __restrict__ wbf) {
    const int bg = blockIdx.x >> 6, ch = blockIdx.x & 63;
    const float4* p = (const float4*)(x + (size_t)bg * CPG * N_TOK) + ch * 512;
    float s = 0.f, ss = 0.f;
#pragma unroll
    for (int r = 0; r < 2; ++r) {
        float4 v = p[threadIdx.x + (r << 8)];
        s  += v.x + v.y + v.z + v.w;
        ss += v.x * v.x + v.y * v.y + v.z * v.z + v.w * v.w;
    }
#pragma unroll
    for (int off = 32; off > 0; off >>= 1) {
        s  += __shfl_down(s, off);
        ss += __shfl_down(ss, off);
    }
    __shared__ float ls[4], lss[4];
    const int lane = threadIdx.x & 63, wid = threadIdx.x >> 6;
    if (lane == 0) { ls[wid] = s; lss[wid] = ss; }

    // weight convert tail (no sync needed; independent outputs)
    const int widx = blockIdx.x * 256 + threadIdx.x;
    float wv = (widx < NQKVW) ? qkv_w[widx] : proj_w[widx - NQKVW];
    wbf[widx] = f2bf(wv);

    __syncthreads();
    if (threadIdx.x == 0) {
        partials[blockIdx.x * 2 + 0] = ls[0] + ls[1] + ls[2] + ls[3];
        partials[blockIdx.x * 2 + 1] = lss[0] + lss[1] + lss[2] + lss[3];
    }
}

// ---------------------------------------------------------------------------
// Kernel 2: fused GroupNorm finalize + apply + QKV GEMM, bf16 MFMA.
// 64x64 tile, 256 threads. Ws staged via global_load_lds from pre-converted
// bf16 weights (XOR-swizzled source, linear LDS dest); Xt reg-staged.
__global__ __launch_bounds__(256) void qkv_gemm_kernel(
    const float* __restrict__ x, const float* __restrict__ partials,
    const float* __restrict__ norm_w, const float* __restrict__ norm_b,
    const unsigned short* __restrict__ wqbf, const float* __restrict__ qkv_b,
    unsigned short* __restrict__ qkvb) {
    __shared__ unsigned short Ws[64][64];   // [o][c] bf16, col-swizzled
    __shared__ unsigned short Xt[64][PSB];  // [n][c] bf16 (transposed xn)
    __shared__ float stat_s[GROUPS][2];
    const int n0 = blockIdx.x * 64;
    const int o0 = blockIdx.y * 64;
    const int b  = blockIdx.z;
    const int tid = threadIdx.x;
    const int lane = tid & 63, w = tid >> 6;
    const int lo = lane & 15, hi = lane >> 4;
    const int srow8 = lane >> 3, sblk = lane & 7;
    const int c16s = (sblk ^ srow8) * 8;    // swizzled source chunk (elements)
    int rcol[2];
#pragma unroll
    for (int c = 0; c < 2; ++c) rcol[c] = (((c * 4 + hi) ^ (lo & 7)) << 3);

    // finalize GroupNorm stats from partials (each block, redundantly; cheap)
    {
        const int g = tid >> 5, sub = tid & 31;
        const float* pp = partials + (((size_t)b * GROUPS + g) * 64 + sub * 2) * 2;
        float4 v = *(const float4*)pp;
        float s = v.x + v.z, ss = v.y + v.w;
#pragma unroll
        for (int off = 16; off > 0; off >>= 1) {
            s  += __shfl_down(s, off, 32);
            ss += __shfl_down(ss, off, 32);
        }
        if (sub == 0) {
            const float inv = 1.f / (float)(CPG * N_TOK);
            float mean = s * inv;
            float var  = ss * inv - mean * mean;
            stat_s[g][0] = mean;
            stat_s[g][1] = rsqrtf(var + EPS);
        }
        __syncthreads();
    }

    f32x4 acc[4] = {};
    for (int k0 = 0; k0 < C_DIM; k0 += 64) {
#pragma unroll
        for (int i = 0; i < 2; ++i) {
            int row = i * 32 + w * 8 + srow8;
            gload16(wqbf + (size_t)(o0 + row) * C_DIM + k0 + c16s, &Ws[i * 32 + w * 8][0]);
        }
#pragma unroll
        for (int r = 0; r < 4; ++r) {
            int idx = tid + (r << 8);
            int crow = idx >> 4, col4 = (idx & 15) << 2;
            int c = k0 + crow;
            int g = c >> 5;
            float ww = norm_w[c] * stat_s[g][1];
            float bb = norm_b[c] - stat_s[g][0] * ww;
            float4 v = *(const float4*)(x + ((size_t)b * C_DIM + c) * N_TOK + n0 + col4);
            Xt[col4 + 0][crow] = f2bf(v.x * ww + bb);
            Xt[col4 + 1][crow] = f2bf(v.y * ww + bb);
            Xt[col4 + 2][crow] = f2bf(v.z * ww + bb);
            Xt[col4 + 3][crow] = f2bf(v.w * ww + bb);
        }
        __syncthreads();   // drains DMA (vmcnt) + ds_writes (lgkm)
#pragma unroll
        for (int ck = 0; ck < 2; ++ck) {
            bf16x8 aw = *(const bf16x8*)&Ws[w * 16 + lo][rcol[ck]];
#pragma unroll
            for (int nb = 0; nb < 4; ++nb)
                acc[nb] = __builtin_amdgcn_mfma_f32_16x16x32_bf16(
                    aw, *(const bf16x8*)&Xt[nb * 16 + lo][ck * 32 + hi * 8], acc[nb], 0, 0, 0);
        }
        __syncthreads();
    }

    const int sidx = o0 >> 8;           // 0=q, 1=k, 2=v
    const int head = (o0 >> 6) & 3;
    const int od = w * 16 + hi * 4;     // d within head (+i)
    float bias[4];
#pragma unroll
    for (int i = 0; i < 4; ++i) bias[i] = qkv_b[o0 + od + i];
    const size_t plane = (size_t)N_TOK * HD;

    if (sidx < 2) {
        const float sc = (sidx == 0) ? QK_SCALE : 1.0f;
        unsigned short* base = qkvb + ((size_t)(sidx * B_DIM + b) * HEADS + head) * plane;
#pragma unroll
        for (int nb = 0; nb < 4; ++nb) {
            int n = n0 + nb * 16 + lo;
            u16x4v o;
#pragma unroll
            for (int i = 0; i < 4; ++i) o[i] = f2bf((acc[nb][i] + bias[i]) * sc);
            *(u16x4v*)(base + (size_t)n * HD + od) = o;
        }
    } else {
        unsigned short* base = qkvb + (size_t)2 * B_DIM * HEADS * plane
                             + ((size_t)b * HEADS + head) * plane;
#pragma unroll
        for (int nb = 0; nb < 4; ++nb)
#pragma unroll
            for (int i = 0; i < 4; ++i)
                base[(size_t)(od + i) * N_TOK + n0 + nb * 16 + lo] = f2bf(acc[nb][i] + bias[i]);
    }
}

// ---------------------------------------------------------------------------
// Kernel 3: bf16 MFMA flash attention (round-10/13 structure, proven 51.4us).
__global__ __launch_bounds__(512, 4) void attn_kernel(const unsigned short* __restrict__ qkvb,
                                                      unsigned short* __restrict__ obuf,
                                                      float* __restrict__ rbuf) {
    const int bh = blockIdx.x & 7;            // b*HEADS + head
    const int ks = (blockIdx.x >> 3) & 3;     // key-split quarter
    const int q0 = (blockIdx.x >> 5) * QBLK;
    const size_t plane = (size_t)N_TOK * HD;
    const unsigned short* Qg  = qkvb + (size_t)bh * plane;
    const unsigned short* Kg  = qkvb + (size_t)(B_DIM * HEADS + bh) * plane;
    const unsigned short* Vtg = qkvb + (size_t)2 * B_DIM * HEADS * plane + (size_t)bh * plane;

    __shared__ unsigned short Ks[2][64][64];  // [buf][perm key row][d] (col-swizzled)
    __shared__ unsigned short Vt[2][64][64];  // [buf][d][key]          (col-swizzled)

    const int tid  = threadIdx.x;
    const int lane = tid & 63;
    const int wid  = tid >> 6;                // 0..7
    const int lo   = lane & 15;
    const int hi   = lane >> 4;

    // Q fragments: frag f covers q = q0 + wid*32 + f*16 + lo, d-chunks c*32+hi*8
    bf16x8 qf[2][2];
#pragma unroll
    for (int f = 0; f < 2; ++f)
#pragma unroll
        for (int c = 0; c < 2; ++c)
            qf[f][c] = *(const bf16x8*)(Qg + (size_t)(q0 + wid * 32 + f * 16 + lo) * HD
                                            + c * 32 + hi * 8);

    const int srow = tid >> 3, sblk = tid & 7;
    const int c16s = (sblk ^ (srow & 7)) * 8;
    const int krow = kperm(srow);
    int rcol[2];
#pragma unroll
    for (int c = 0; c < 2; ++c) rcol[c] = (((c * 4 + hi) ^ (lo & 7)) << 3);

#define STAGE_KV(bufi, kbase)                                                          \
    do {                                                                               \
        gload16(Kg + (size_t)((kbase) + krow) * HD + c16s, &Ks[bufi][wid * 8][0]);     \
        gload16(Vtg + (size_t)srow * N_TOK + (kbase) + c16s, &Vt[bufi][wid * 8][0]);   \
    } while (0)

    const int kt0 = ks * (NKT / KSPLIT), ktE = kt0 + NKT / KSPLIT;

    f32x4 acc[2][4] = {};   // acc[f][db][i] = O^T[d=db*16+hi*4+i][q of frag f]
    float m[2] = {-1e30f, -1e30f}, l[2] = {0.f, 0.f};

    STAGE_KV(0, kt0 * 64);
    __syncthreads();   // drains the DMA (vmcnt 0) + barrier

    for (int kt = kt0; kt < ktE; ++kt) {
        const int cur = kt & 1;
        if (kt + 1 < ktE) STAGE_KV(cur ^ 1, (kt + 1) * 64);

        // S^T = K Q^T for BOTH frags; each K fragment read once, used twice.
        f32x4 s4[2][4] = {};
        __builtin_amdgcn_s_setprio(1);
#pragma unroll
        for (int kb = 0; kb < 4; ++kb)
#pragma unroll
            for (int c = 0; c < 2; ++c) {
                bf16x8 kf = *(const bf16x8*)&Ks[cur][kb * 16 + lo][rcol[c]];
                s4[0][kb] = __builtin_amdgcn_mfma_f32_16x16x32_bf16(kf, qf[0][c], s4[0][kb], 0, 0, 0);
                s4[1][kb] = __builtin_amdgcn_mfma_f32_16x16x32_bf16(kf, qf[1][c], s4[1][kb], 0, 0, 0);
            }
        __builtin_amdgcn_s_setprio(0);

        // softmax per frag (lane-local; cross-lane only in rare rescale branch)
        bf16x8 pf[2][2];
#pragma unroll
        for (int f = 0; f < 2; ++f) {
            float r0 = fmaxf(fmaxf(fmaxf(s4[f][0][0], s4[f][0][1]), s4[f][0][2]), s4[f][0][3]);
            float r1 = fmaxf(fmaxf(fmaxf(s4[f][1][0], s4[f][1][1]), s4[f][1][2]), s4[f][1][3]);
            float r2 = fmaxf(fmaxf(fmaxf(s4[f][2][0], s4[f][2][1]), s4[f][2][2]), s4[f][2][3]);
            float r3 = fmaxf(fmaxf(fmaxf(s4[f][3][0], s4[f][3][1]), s4[f][3][2]), s4[f][3][3]);
            float rm = fmaxf(fmaxf(fmaxf(r0, r1), r2), r3);

            // defer-max (T13) with LOCAL max check
            if (__any(rm > m[f] + 8.0f)) {
                float rmx = rm;
                rmx = fmaxf(rmx, __shfl_xor(rmx, 16));
                rmx = fmaxf(rmx, __shfl_xor(rmx, 32));
                const float mn = fmaxf(m[f], rmx);
                const float fi = exp2_fast(m[f] - mn);
                m[f] = mn;
                l[f] *= fi;
#pragma unroll
                for (int db = 0; db < 4; ++db)
#pragma unroll
                    for (int i = 0; i < 4; ++i) acc[f][db][i] *= fi;
            }

            float p[4][4];
            float ps = 0.f;
#pragma unroll
            for (int kb = 0; kb < 4; ++kb)
#pragma unroll
                for (int i = 0; i < 4; ++i) {
                    p[kb][i] = exp2_fast(s4[f][kb][i] - m[f]);
                    ps += p[kb][i];
                }
            l[f] += ps;

            // pack P into PV B-fragment: pf[f][c][j] = p[2c + (j>>2)][j&3]
#pragma unroll
            for (int c = 0; c < 2; ++c)
#pragma unroll
                for (int j = 0; j < 8; ++j) pf[f][c][j] = (__bf16)p[2 * c + (j >> 2)][j & 3];
        }

        // O^T += V^T P^T for BOTH frags; each V fragment read once, used twice.
        __builtin_amdgcn_s_setprio(1);
#pragma unroll
        for (int db = 0; db < 4; ++db)
#pragma unroll
            for (int c = 0; c < 2; ++c) {
                bf16x8 vf = *(const bf16x8*)&Vt[cur][db * 16 + lo][rcol[c]];
                acc[0][db] = __builtin_amdgcn_mfma_f32_16x16x32_bf16(vf, pf[0][c], acc[0][db], 0, 0, 0);
                acc[1][db] = __builtin_amdgcn_mfma_f32_16x16x32_bf16(vf, pf[1][c], acc[1][db], 0, 0, 0);
            }
        __builtin_amdgcn_s_setprio(0);

        __syncthreads();
    }
#undef STAGE_KV

    // epilogue per frag: normalized bf16 partial O + log-sum-exp r
#pragma unroll
    for (int f = 0; f < 2; ++f) {
        float l1 = l[f] + __shfl_xor(l[f], 16);
        float lt = l1 + __shfl_xor(l1, 32);
        const float inv = 1.f / lt;
        const int n = q0 + wid * 32 + f * 16 + lo;
        unsigned short* ob = obuf + ((size_t)(ks * 8 + bh) * N_TOK + n) * HD;
#pragma unroll
        for (int db = 0; db < 4; ++db) {
            u16x4v o;
#pragma unroll
            for (int i = 0; i < 4; ++i) o[i] = f2bf(acc[f][db][i] * inv);
            *(u16x4v*)(ob + db * 16 + hi * 4) = o;
        }
        if (hi == 0)
            rbuf[(size_t)(ks * 8 + bh) * N_TOK + n] = m[f] + __builtin_amdgcn_logf(lt);
    }
}

// ---------------------------------------------------------------------------
// Kernel 4: output projection + bias + residual, bf16 MFMA, with the K-split
// combine fused into the Hs staging. Ws staged via global_load_lds (swizzled);
// Hs reg-staged (combine math) into a PSB-padded tile.
__global__ __launch_bounds__(256) void proj_kernel(
    const unsigned short* __restrict__ obuf, const float* __restrict__ rbuf,
    const unsigned short* __restrict__ wpbf, const float* __restrict__ proj_b,
    const float* __restrict__ x, float* __restrict__ out) {
    __shared__ unsigned short Ws[64][64];   // [o][c] bf16, col-swizzled (DMA)
    __shared__ unsigned short Hs[64][PSB];  // [n][c-within-head], reg-staged
    const int n0 = blockIdx.x * 64;
    const int o0 = blockIdx.y * 64;
    const int b  = blockIdx.z;
    const int tid = threadIdx.x;
    const int lane = tid & 63, w = tid >> 6;
    const int lo = lane & 15, hi = lane >> 4;
    const int srow8 = lane >> 3, sblk = lane & 7;
    const int c16s = (sblk ^ srow8) * 8;
    int rcol[2];
#pragma unroll
    for (int c = 0; c < 2; ++c) rcol[c] = (((c * 4 + hi) ^ (lo & 7)) << 3);

    f32x4 acc[4] = {};
    for (int k0 = 0; k0 < C_DIM; k0 += 64) {
        // Ws via DMA (2 instrs / wave)
#pragma unroll
        for (int i = 0; i < 2; ++i) {
            int row = i * 32 + w * 8 + srow8;
            gload16(wpbf + (size_t)(o0 + row) * C_DIM + k0 + c16s, &Ws[i * 32 + w * 8][0]);
        }
        // stage h[n][k0..k0+64): head = k0>>6; combine the 4 K-split partials
        {
            const int head = k0 >> 6;
            const int bh = b * HEADS + head;
#pragma unroll
            for (int r = 0; r < 2; ++r) {
                int idx = tid + (r << 8);
                int row = idx >> 3, blk = idx & 7;   // n-row in tile, 8-d chunk
                int n = n0 + row;
                float rr[KSPLIT], M = -1e30f;
#pragma unroll
                for (int k = 0; k < KSPLIT; ++k) {
                    rr[k] = rbuf[(size_t)(k * 8 + bh) * N_TOK + n];
                    M = fmaxf(M, rr[k]);
                }
                float wk[KSPLIT], tot = 0.f;
#pragma unroll
                for (int k = 0; k < KSPLIT; ++k) { wk[k] = exp2_fast(rr[k] - M); tot += wk[k]; }
                const float inv = 1.f / tot;
                float a[8] = {};
#pragma unroll
                for (int k = 0; k < KSPLIT; ++k) {
                    u16x8v v = *(const u16x8v*)(obuf
                        + ((size_t)(k * 8 + bh) * N_TOK + n) * HD + blk * 8);
#pragma unroll
                    for (int j = 0; j < 8; ++j) a[j] += wk[k] * bf2f(v[j]);
                }
                u16x8v o;
#pragma unroll
                for (int j = 0; j < 8; ++j) o[j] = f2bf(a[j] * inv);
                *(u16x8v*)&Hs[row][blk * 8] = o;
            }
        }
        __syncthreads();   // drains DMA (vmcnt) + ds_writes (lgkm)
#pragma unroll
        for (int ck = 0; ck < 2; ++ck) {
            bf16x8 aw = *(const bf16x8*)&Ws[w * 16 + lo][rcol[ck]];
#pragma unroll
            for (int nb = 0; nb < 4; ++nb)
                acc[nb] = __builtin_amdgcn_mfma_f32_16x16x32_bf16(
                    aw, *(const bf16x8*)&Hs[nb * 16 + lo][ck * 32 + hi * 8], acc[nb], 0, 0, 0);
        }
        __syncthreads();
    }

#pragma unroll
    for (int nb = 0; nb < 4; ++nb) {
#pragma unroll
        for (int i = 0; i < 4; ++i) {
            int o = o0 + w * 16 + hi * 4 + i;
            size_t addr = ((size_t)b * C_DIM + o) * N_TOK + n0 + nb * 16 + lo;
            out[addr] = acc[nb][i] + proj_b[o] + x[addr];
        }
    }
}

// ---------------------------------------------------------------------------
extern "C" void kernel_launch(void* const* d_in, const int* in_sizes, int n_in,
                              void* d_out, int out_size, void* d_ws, size_t ws_size,
                              hipStream_t stream) {
    const float* x      = (const float*)d_in[0];
    const float* norm_w = (const float*)d_in[1];
    const float* norm_b = (const float*)d_in[2];
    const float* qkv_w  = (const float*)d_in[3];
    const float* qkv_b  = (const float*)d_in[4];
    const float* proj_w = (const float*)d_in[5];
    const float* proj_b = (const float*)d_in[6];
    float* out = (float*)d_out;

    // ws: partials f32[2048] (8KB) | wbf u16[262144] (512KB) | qkvb bf16 (12.6MB)
    //   | obuf bf16 [4][8][N][HD] (16.8MB) | rbuf f32 [4][8][N] (512KB) ~= 30.4MB
    float* partials = (float*)d_ws;
    unsigned short* wbf = (unsigned short*)(partials + 2048);
    unsigned short* qkvb = wbf + (NQKVW + NPROJW);
    unsigned short* obuf = qkvb + (size_t)3 * B_DIM * HEADS * N_TOK * HD;
    float* rbuf = (float*)(obuf + (size_t)KSPLIT * B_DIM * HEADS * N_TOK * HD);
    const unsigned short* wqbf = wbf;
    const unsigned short* wpbf = wbf + NQKVW;

    gn_part_kernel<<<B_DIM * GROUPS * 64, 256, 0, stream>>>(x, qkv_w, proj_w, partials, wbf);
    qkv_gemm_kernel<<<dim3(N_TOK / 64, 3 * C_DIM / 64, B_DIM), 256, 0, stream>>>(
        x, partials, norm_w, norm_b, wqbf, qkv_b, qkvb);
    attn_kernel<<<(N_TOK / QBLK) * B_DIM * HEADS * KSPLIT, 512, 0, stream>>>(qkvb, obuf, rbuf);
    proj_kernel<<<dim3(N_TOK / 64, C_DIM / 64, B_DIM), 256, 0, stream>>>(
        obuf, rbuf, wpbf, proj_b, x, out);
}

// Round 16
// 80.628 us; speedup vs baseline: 1.2116x; 1.0894x over previous
//
#include <hip/hip_runtime.h>
#include <math.h>

#define B_DIM 2
#define C_DIM 256
#define N_TOK 4096      // 16*16*16
#define HEADS 4
#define HD 64
#define GROUPS 8
#define CPG (C_DIM / GROUPS)   // 32
#define EPS 1e-5f
#define PSB 72          // padded bf16 LDS row stride (reg-staged tiles)
#define QK_SCALE 0.180336880f  // 0.125 * log2(e), folded into Q
#define KSPLIT 4
#define NKT (N_TOK / 64)       // 64 key tiles total
#define QBLK 256               // queries per attention block (8 waves x 2 frags x 16 q)
#define NQKVW (3 * C_DIM * C_DIM)   // 196608 qkv_w elems
#define NPROJW (C_DIM * C_DIM)      // 65536 proj_w elems

typedef __bf16 bf16x8 __attribute__((ext_vector_type(8)));
typedef float  f32x4  __attribute__((ext_vector_type(4)));
typedef unsigned short u16x4v __attribute__((ext_vector_type(4)));
typedef unsigned short u16x8v __attribute__((ext_vector_type(8)));

__device__ __forceinline__ unsigned short f2bf(float f) {
    return __builtin_bit_cast(unsigned short, (__bf16)f);
}
__device__ __forceinline__ float bf2f(unsigned short u) {
    return (float)__builtin_bit_cast(__bf16, u);
}
// raw v_exp_f32 (2^x); inputs bounded so no OCML fixup needed
__device__ __forceinline__ float exp2_fast(float x) { return __builtin_amdgcn_exp2f(x); }

// async global->LDS, 16B per lane, wave-uniform LDS base (linear dest)
__device__ __forceinline__ void gload16(const unsigned short* g, unsigned short* l) {
    __builtin_amdgcn_global_load_lds(
        (const __attribute__((address_space(1))) unsigned int*)g,
        (__attribute__((address_space(3))) unsigned int*)l, 16, 0, 0);
}

// K-staging row permutation: [b5 b4 b3 b2 b1 b0] -> [b5 b3 b2 b4 b1 b0].
// Makes the S^T output registers exactly the PV B-fragment.
__device__ __forceinline__ int kperm(int r) {
    return (r & 0x23) | ((r & 0x0C) << 1) | ((r & 0x10) >> 2);
}

// ---------------------------------------------------------------------------
// Kernel 1: GroupNorm partial sums (1024 blocks) + weight f32->bf16 convert
// tail (262144 = 1024*256 elems, one per thread, coalesced).
__global__ __launch_bounds__(256) void gn_part_kernel(const float* __restrict__ x,
                                                      const float* __restrict__ qkv_w,
                                                      const float* __restrict__ proj_w,
                                                      float* __restrict__ partials,
                                                      unsigned short* __restrict__ wbf) {
    const int bg = blockIdx.x >> 6, ch = blockIdx.x & 63;
    const float4* p = (const float4*)(x + (size_t)bg * CPG * N_TOK) + ch * 512;
    float s = 0.f, ss = 0.f;
#pragma unroll
    for (int r = 0; r < 2; ++r) {
        float4 v = p[threadIdx.x + (r << 8)];
        s  += v.x + v.y + v.z + v.w;
        ss += v.x * v.x + v.y * v.y + v.z * v.z + v.w * v.w;
    }
#pragma unroll
    for (int off = 32; off > 0; off >>= 1) {
        s  += __shfl_down(s, off);
        ss += __shfl_down(ss, off);
    }
    __shared__ float ls[4], lss[4];
    const int lane = threadIdx.x & 63, wid = threadIdx.x >> 6;
    if (lane == 0) { ls[wid] = s; lss[wid] = ss; }

    // weight convert tail (no sync needed; independent outputs)
    const int widx = blockIdx.x * 256 + threadIdx.x;
    float wv = (widx < NQKVW) ? qkv_w[widx] : proj_w[widx - NQKVW];
    wbf[widx] = f2bf(wv);

    __syncthreads();
    if (threadIdx.x == 0) {
        partials[blockIdx.x * 2 + 0] = ls[0] + ls[1] + ls[2] + ls[3];
        partials[blockIdx.x * 2 + 1] = lss[0] + lss[1] + lss[2] + lss[3];
    }
}

// ---------------------------------------------------------------------------
// Kernel 1b: GroupNorm finalize + apply + transpose -> xnT bf16 [b][n][c].
// Block covers 64 c-rows x 64 n-cols; 512 blocks. Done ONCE (qkv read it 12x).
__global__ __launch_bounds__(256) void xnorm_kernel(const float* __restrict__ x,
                                                    const float* __restrict__ partials,
                                                    const float* __restrict__ norm_w,
                                                    const float* __restrict__ norm_b,
                                                    unsigned short* __restrict__ xnT) {
    __shared__ unsigned short Xt[64][PSB];  // [n][c] bf16
    __shared__ float stat_s[GROUPS][2];
    const int n0 = blockIdx.x * 64;
    const int c0 = blockIdx.y * 64;
    const int b  = blockIdx.z;
    const int tid = threadIdx.x;

    // finalize GroupNorm stats from partials
    {
        const int g = tid >> 5, sub = tid & 31;
        const float* pp = partials + (((size_t)b * GROUPS + g) * 64 + sub * 2) * 2;
        float4 v = *(const float4*)pp;
        float s = v.x + v.z, ss = v.y + v.w;
#pragma unroll
        for (int off = 16; off > 0; off >>= 1) {
            s  += __shfl_down(s, off, 32);
            ss += __shfl_down(ss, off, 32);
        }
        if (sub == 0) {
            const float inv = 1.f / (float)(CPG * N_TOK);
            float mean = s * inv;
            float var  = ss * inv - mean * mean;
            stat_s[g][0] = mean;
            stat_s[g][1] = rsqrtf(var + EPS);
        }
        __syncthreads();
    }

    // read 64c x 64n (coalesced along n), normalize, transpose into LDS
#pragma unroll
    for (int r = 0; r < 4; ++r) {
        int idx = tid + (r << 8);
        int crow = idx >> 4, col4 = (idx & 15) << 2;
        int c = c0 + crow;
        int g = c >> 5;
        float ww = norm_w[c] * stat_s[g][1];
        float bb = norm_b[c] - stat_s[g][0] * ww;
        float4 v = *(const float4*)(x + ((size_t)b * C_DIM + c) * N_TOK + n0 + col4);
        Xt[col4 + 0][crow] = f2bf(v.x * ww + bb);
        Xt[col4 + 1][crow] = f2bf(v.y * ww + bb);
        Xt[col4 + 2][crow] = f2bf(v.z * ww + bb);
        Xt[col4 + 3][crow] = f2bf(v.w * ww + bb);
    }
    __syncthreads();

    // write xnT[b][n0+row][c0 + blk*8], 16B per thread
#pragma unroll
    for (int r = 0; r < 2; ++r) {
        int idx = tid + (r << 8);
        int row = idx >> 3, blk = idx & 7;
        *(u16x8v*)(xnT + ((size_t)b * N_TOK + n0 + row) * C_DIM + c0 + blk * 8) =
            *(const u16x8v*)&Xt[row][blk * 8];
    }
}

// ---------------------------------------------------------------------------
// Kernel 2: QKV GEMM, bf16 MFMA, pure-2-DMA (m97 recipe): Ws and Xs both via
// global_load_lds with XOR-swizzled source, linear LDS dest. Zero staging VALU.
__global__ __launch_bounds__(256) void qkv_gemm_kernel(
    const unsigned short* __restrict__ xnT, const unsigned short* __restrict__ wqbf,
    const float* __restrict__ qkv_b, unsigned short* __restrict__ qkvb) {
    __shared__ unsigned short Ws[64][64];   // [o][c] bf16, col-swizzled
    __shared__ unsigned short Xs[64][64];   // [n][c] bf16, col-swizzled
    const int n0 = blockIdx.x * 64;
    const int o0 = blockIdx.y * 64;
    const int b  = blockIdx.z;
    const int tid = threadIdx.x;
    const int lane = tid & 63, w = tid >> 6;
    const int lo = lane & 15, hi = lane >> 4;
    const int srow8 = lane >> 3, sblk = lane & 7;
    const int c16s = (sblk ^ srow8) * 8;    // swizzled source chunk (elements)
    int rcol[2];
#pragma unroll
    for (int c = 0; c < 2; ++c) rcol[c] = (((c * 4 + hi) ^ (lo & 7)) << 3);

    f32x4 acc[4] = {};
    for (int k0 = 0; k0 < C_DIM; k0 += 64) {
#pragma unroll
        for (int i = 0; i < 2; ++i) {
            int row = i * 32 + w * 8 + srow8;
            gload16(wqbf + (size_t)(o0 + row) * C_DIM + k0 + c16s, &Ws[i * 32 + w * 8][0]);
            gload16(xnT + ((size_t)b * N_TOK + n0 + row) * C_DIM + k0 + c16s,
                    &Xs[i * 32 + w * 8][0]);
        }
        __syncthreads();   // drains DMA
#pragma unroll
        for (int ck = 0; ck < 2; ++ck) {
            bf16x8 aw = *(const bf16x8*)&Ws[w * 16 + lo][rcol[ck]];
#pragma unroll
            for (int nb = 0; nb < 4; ++nb)
                acc[nb] = __builtin_amdgcn_mfma_f32_16x16x32_bf16(
                    aw, *(const bf16x8*)&Xs[nb * 16 + lo][rcol[ck]], acc[nb], 0, 0, 0);
        }
        __syncthreads();
    }

    const int sidx = o0 >> 8;           // 0=q, 1=k, 2=v
    const int head = (o0 >> 6) & 3;
    const int od = w * 16 + hi * 4;     // d within head (+i)
    float bias[4];
#pragma unroll
    for (int i = 0; i < 4; ++i) bias[i] = qkv_b[o0 + od + i];
    const size_t plane = (size_t)N_TOK * HD;

    if (sidx < 2) {
        const float sc = (sidx == 0) ? QK_SCALE : 1.0f;
        unsigned short* base = qkvb + ((size_t)(sidx * B_DIM + b) * HEADS + head) * plane;
#pragma unroll
        for (int nb = 0; nb < 4; ++nb) {
            int n = n0 + nb * 16 + lo;
            u16x4v o;
#pragma unroll
            for (int i = 0; i < 4; ++i) o[i] = f2bf((acc[nb][i] + bias[i]) * sc);
            *(u16x4v*)(base + (size_t)n * HD + od) = o;
        }
    } else {
        unsigned short* base = qkvb + (size_t)2 * B_DIM * HEADS * plane
                             + ((size_t)b * HEADS + head) * plane;
#pragma unroll
        for (int nb = 0; nb < 4; ++nb)
#pragma unroll
            for (int i = 0; i < 4; ++i)
                base[(size_t)(od + i) * N_TOK + n0 + nb * 16 + lo] = f2bf(acc[nb][i] + bias[i]);
    }
}

// ---------------------------------------------------------------------------
// Kernel 3: bf16 MFMA flash attention (round-10/13 structure, proven 51.4us).
__global__ __launch_bounds__(512, 4) void attn_kernel(const unsigned short* __restrict__ qkvb,
                                                      unsigned short* __restrict__ obuf,
                                                      float* __restrict__ rbuf) {
    const int bh = blockIdx.x & 7;            // b*HEADS + head
    const int ks = (blockIdx.x >> 3) & 3;     // key-split quarter
    const int q0 = (blockIdx.x >> 5) * QBLK;
    const size_t plane = (size_t)N_TOK * HD;
    const unsigned short* Qg  = qkvb + (size_t)bh * plane;
    const unsigned short* Kg  = qkvb + (size_t)(B_DIM * HEADS + bh) * plane;
    const unsigned short* Vtg = qkvb + (size_t)2 * B_DIM * HEADS * plane + (size_t)bh * plane;

    __shared__ unsigned short Ks[2][64][64];  // [buf][perm key row][d] (col-swizzled)
    __shared__ unsigned short Vt[2][64][64];  // [buf][d][key]          (col-swizzled)

    const int tid  = threadIdx.x;
    const int lane = tid & 63;
    const int wid  = tid >> 6;                // 0..7
    const int lo   = lane & 15;
    const int hi   = lane >> 4;

    // Q fragments: frag f covers q = q0 + wid*32 + f*16 + lo, d-chunks c*32+hi*8
    bf16x8 qf[2][2];
#pragma unroll
    for (int f = 0; f < 2; ++f)
#pragma unroll
        for (int c = 0; c < 2; ++c)
            qf[f][c] = *(const bf16x8*)(Qg + (size_t)(q0 + wid * 32 + f * 16 + lo) * HD
                                            + c * 32 + hi * 8);

    const int srow = tid >> 3, sblk = tid & 7;
    const int c16s = (sblk ^ (srow & 7)) * 8;
    const int krow = kperm(srow);
    int rcol[2];
#pragma unroll
    for (int c = 0; c < 2; ++c) rcol[c] = (((c * 4 + hi) ^ (lo & 7)) << 3);

#define STAGE_KV(bufi, kbase)                                                          \
    do {                                                                               \
        gload16(Kg + (size_t)((kbase) + krow) * HD + c16s, &Ks[bufi][wid * 8][0]);     \
        gload16(Vtg + (size_t)srow * N_TOK + (kbase) + c16s, &Vt[bufi][wid * 8][0]);   \
    } while (0)

    const int kt0 = ks * (NKT / KSPLIT), ktE = kt0 + NKT / KSPLIT;

    f32x4 acc[2][4] = {};   // acc[f][db][i] = O^T[d=db*16+hi*4+i][q of frag f]
    float m[2] = {-1e30f, -1e30f}, l[2] = {0.f, 0.f};

    STAGE_KV(0, kt0 * 64);
    __syncthreads();   // drains the DMA (vmcnt 0) + barrier

    for (int kt = kt0; kt < ktE; ++kt) {
        const int cur = kt & 1;
        if (kt + 1 < ktE) STAGE_KV(cur ^ 1, (kt + 1) * 64);

        // S^T = K Q^T for BOTH frags; each K fragment read once, used twice.
        f32x4 s4[2][4] = {};
        __builtin_amdgcn_s_setprio(1);
#pragma unroll
        for (int kb = 0; kb < 4; ++kb)
#pragma unroll
            for (int c = 0; c < 2; ++c) {
                bf16x8 kf = *(const bf16x8*)&Ks[cur][kb * 16 + lo][rcol[c]];
                s4[0][kb] = __builtin_amdgcn_mfma_f32_16x16x32_bf16(kf, qf[0][c], s4[0][kb], 0, 0, 0);
                s4[1][kb] = __builtin_amdgcn_mfma_f32_16x16x32_bf16(kf, qf[1][c], s4[1][kb], 0, 0, 0);
            }
        __builtin_amdgcn_s_setprio(0);

        // softmax per frag (lane-local; cross-lane only in rare rescale branch)
        bf16x8 pf[2][2];
#pragma unroll
        for (int f = 0; f < 2; ++f) {
            float r0 = fmaxf(fmaxf(fmaxf(s4[f][0][0], s4[f][0][1]), s4[f][0][2]), s4[f][0][3]);
            float r1 = fmaxf(fmaxf(fmaxf(s4[f][1][0], s4[f][1][1]), s4[f][1][2]), s4[f][1][3]);
            float r2 = fmaxf(fmaxf(fmaxf(s4[f][2][0], s4[f][2][1]), s4[f][2][2]), s4[f][2][3]);
            float r3 = fmaxf(fmaxf(fmaxf(s4[f][3][0], s4[f][3][1]), s4[f][3][2]), s4[f][3][3]);
            float rm = fmaxf(fmaxf(fmaxf(r0, r1), r2), r3);

            // defer-max (T13) with LOCAL max check
            if (__any(rm > m[f] + 8.0f)) {
                float rmx = rm;
                rmx = fmaxf(rmx, __shfl_xor(rmx, 16));
                rmx = fmaxf(rmx, __shfl_xor(rmx, 32));
                const float mn = fmaxf(m[f], rmx);
                const float fi = exp2_fast(m[f] - mn);
                m[f] = mn;
                l[f] *= fi;
#pragma unroll
                for (int db = 0; db < 4; ++db)
#pragma unroll
                    for (int i = 0; i < 4; ++i) acc[f][db][i] *= fi;
            }

            float p[4][4];
            float ps = 0.f;
#pragma unroll
            for (int kb = 0; kb < 4; ++kb)
#pragma unroll
                for (int i = 0; i < 4; ++i) {
                    p[kb][i] = exp2_fast(s4[f][kb][i] - m[f]);
                    ps += p[kb][i];
                }
            l[f] += ps;

            // pack P into PV B-fragment: pf[f][c][j] = p[2c + (j>>2)][j&3]
#pragma unroll
            for (int c = 0; c < 2; ++c)
#pragma unroll
                for (int j = 0; j < 8; ++j) pf[f][c][j] = (__bf16)p[2 * c + (j >> 2)][j & 3];
        }

        // O^T += V^T P^T for BOTH frags; each V fragment read once, used twice.
        __builtin_amdgcn_s_setprio(1);
#pragma unroll
        for (int db = 0; db < 4; ++db)
#pragma unroll
            for (int c = 0; c < 2; ++c) {
                bf16x8 vf = *(const bf16x8*)&Vt[cur][db * 16 + lo][rcol[c]];
                acc[0][db] = __builtin_amdgcn_mfma_f32_16x16x32_bf16(vf, pf[0][c], acc[0][db], 0, 0, 0);
                acc[1][db] = __builtin_amdgcn_mfma_f32_16x16x32_bf16(vf, pf[1][c], acc[1][db], 0, 0, 0);
            }
        __builtin_amdgcn_s_setprio(0);

        __syncthreads();
    }
#undef STAGE_KV

    // epilogue per frag: normalized bf16 partial O + log-sum-exp r
#pragma unroll
    for (int f = 0; f < 2; ++f) {
        float l1 = l[f] + __shfl_xor(l[f], 16);
        float lt = l1 + __shfl_xor(l1, 32);
        const float inv = 1.f / lt;
        const int n = q0 + wid * 32 + f * 16 + lo;
        unsigned short* ob = obuf + ((size_t)(ks * 8 + bh) * N_TOK + n) * HD;
#pragma unroll
        for (int db = 0; db < 4; ++db) {
            u16x4v o;
#pragma unroll
            for (int i = 0; i < 4; ++i) o[i] = f2bf(acc[f][db][i] * inv);
            *(u16x4v*)(ob + db * 16 + hi * 4) = o;
        }
        if (hi == 0)
            rbuf[(size_t)(ks * 8 + bh) * N_TOK + n] = m[f] + __builtin_amdgcn_logf(lt);
    }
}

// ---------------------------------------------------------------------------
// Kernel 4: output projection + bias + residual, bf16 MFMA, with the K-split
// combine fused into the Hs staging. Ws staged via global_load_lds (swizzled);
// Hs reg-staged (combine math) into a PSB-padded tile.
__global__ __launch_bounds__(256) void proj_kernel(
    const unsigned short* __restrict__ obuf, const float* __restrict__ rbuf,
    const unsigned short* __restrict__ wpbf, const float* __restrict__ proj_b,
    const float* __restrict__ x, float* __restrict__ out) {
    __shared__ unsigned short Ws[64][64];   // [o][c] bf16, col-swizzled (DMA)
    __shared__ unsigned short Hs[64][PSB];  // [n][c-within-head], reg-staged
    const int n0 = blockIdx.x * 64;
    const int o0 = blockIdx.y * 64;
    const int b  = blockIdx.z;
    const int tid = threadIdx.x;
    const int lane = tid & 63, w = tid >> 6;
    const int lo = lane & 15, hi = lane >> 4;
    const int srow8 = lane >> 3, sblk = lane & 7;
    const int c16s = (sblk ^ srow8) * 8;
    int rcol[2];
#pragma unroll
    for (int c = 0; c < 2; ++c) rcol[c] = (((c * 4 + hi) ^ (lo & 7)) << 3);

    f32x4 acc[4] = {};
    for (int k0 = 0; k0 < C_DIM; k0 += 64) {
        // Ws via DMA (2 instrs / wave)
#pragma unroll
        for (int i = 0; i < 2; ++i) {
            int row = i * 32 + w * 8 + srow8;
            gload16(wpbf + (size_t)(o0 + row) * C_DIM + k0 + c16s, &Ws[i * 32 + w * 8][0]);
        }
        // stage h[n][k0..k0+64): head = k0>>6; combine the 4 K-split partials
        {
            const int head = k0 >> 6;
            const int bh = b * HEADS + head;
#pragma unroll
            for (int r = 0; r < 2; ++r) {
                int idx = tid + (r << 8);
                int row = idx >> 3, blk = idx & 7;   // n-row in tile, 8-d chunk
                int n = n0 + row;
                float rr[KSPLIT], M = -1e30f;
#pragma unroll
                for (int k = 0; k < KSPLIT; ++k) {
                    rr[k] = rbuf[(size_t)(k * 8 + bh) * N_TOK + n];
                    M = fmaxf(M, rr[k]);
                }
                float wk[KSPLIT], tot = 0.f;
#pragma unroll
                for (int k = 0; k < KSPLIT; ++k) { wk[k] = exp2_fast(rr[k] - M); tot += wk[k]; }
                const float inv = 1.f / tot;
                float a[8] = {};
#pragma unroll
                for (int k = 0; k < KSPLIT; ++k) {
                    u16x8v v = *(const u16x8v*)(obuf
                        + ((size_t)(k * 8 + bh) * N_TOK + n) * HD + blk * 8);
#pragma unroll
                    for (int j = 0; j < 8; ++j) a[j] += wk[k] * bf2f(v[j]);
                }
                u16x8v o;
#pragma unroll
                for (int j = 0; j < 8; ++j) o[j] = f2bf(a[j] * inv);
                *(u16x8v*)&Hs[row][blk * 8] = o;
            }
        }
        __syncthreads();   // drains DMA (vmcnt) + ds_writes (lgkm)
#pragma unroll
        for (int ck = 0; ck < 2; ++ck) {
            bf16x8 aw = *(const bf16x8*)&Ws[w * 16 + lo][rcol[ck]];
#pragma unroll
            for (int nb = 0; nb < 4; ++nb)
                acc[nb] = __builtin_amdgcn_mfma_f32_16x16x32_bf16(
                    aw, *(const bf16x8*)&Hs[nb * 16 + lo][ck * 32 + hi * 8], acc[nb], 0, 0, 0);
        }
        __syncthreads();
    }

#pragma unroll
    for (int nb = 0; nb < 4; ++nb) {
#pragma unroll
        for (int i = 0; i < 4; ++i) {
            int o = o0 + w * 16 + hi * 4 + i;
            size_t addr = ((size_t)b * C_DIM + o) * N_TOK + n0 + nb * 16 + lo;
            out[addr] = acc[nb][i] + proj_b[o] + x[addr];
        }
    }
}

// ---------------------------------------------------------------------------
extern "C" void kernel_launch(void* const* d_in, const int* in_sizes, int n_in,
                              void* d_out, int out_size, void* d_ws, size_t ws_size,
                              hipStream_t stream) {
    const float* x      = (const float*)d_in[0];
    const float* norm_w = (const float*)d_in[1];
    const float* norm_b = (const float*)d_in[2];
    const float* qkv_w  = (const float*)d_in[3];
    const float* qkv_b  = (const float*)d_in[4];
    const float* proj_w = (const float*)d_in[5];
    const float* proj_b = (const float*)d_in[6];
    float* out = (float*)d_out;

    // ws: partials f32[2048] (8KB) | wbf u16[262144] (512KB) | xnT bf16 (4.2MB)
    //   | qkvb bf16 (12.6MB) | obuf bf16 [4][8][N][HD] (16.8MB)
    //   | rbuf f32 [4][8][N] (512KB)  ~= 34.6MB
    float* partials = (float*)d_ws;
    unsigned short* wbf = (unsigned short*)(partials + 2048);
    unsigned short* xnT = wbf + (NQKVW + NPROJW);
    unsigned short* qkvb = xnT + (size_t)B_DIM * N_TOK * C_DIM;
    unsigned short* obuf = qkvb + (size_t)3 * B_DIM * HEADS * N_TOK * HD;
    float* rbuf = (float*)(obuf + (size_t)KSPLIT * B_DIM * HEADS * N_TOK * HD);
    const unsigned short* wqbf = wbf;
    const unsigned short* wpbf = wbf + NQKVW;

    gn_part_kernel<<<B_DIM * GROUPS * 64, 256, 0, stream>>>(x, qkv_w, proj_w, partials, wbf);
    xnorm_kernel<<<dim3(N_TOK / 64, C_DIM / 64, B_DIM), 256, 0, stream>>>(
        x, partials, norm_w, norm_b, xnT);
    qkv_gemm_kernel<<<dim3(N_TOK / 64, 3 * C_DIM / 64, B_DIM), 256, 0, stream>>>(
        xnT, wqbf, qkv_b, qkvb);
    attn_kernel<<<(N_TOK / QBLK) * B_DIM * HEADS * KSPLIT, 512, 0, stream>>>(qkvb, obuf, rbuf);
    proj_kernel<<<dim3(N_TOK / 64, C_DIM / 64, B_DIM), 256, 0, stream>>>(
        obuf, rbuf, wpbf, proj_b, x, out);
}

// Round 17
// 78.834 us; speedup vs baseline: 1.2392x; 1.0228x over previous
//
#include <hip/hip_runtime.h>
#include <math.h>

#define B_DIM 2
#define C_DIM 256
#define N_TOK 4096      // 16*16*16
#define HEADS 4
#define HD 64
#define GROUPS 8
#define CPG (C_DIM / GROUPS)   // 32
#define EPS 1e-5f
#define PSB 72          // padded bf16 LDS row stride (reg-staged tiles)
#define QK_SCALE 0.180336880f  // 0.125 * log2(e), folded into Q
#define KSPLIT 4
#define NKT (N_TOK / 64)       // 64 key tiles total
#define QBLK 256               // queries per attention block (8 waves x 2 frags x 16 q)
#define NQKVW (3 * C_DIM * C_DIM)   // 196608 qkv_w elems
#define NPROJW (C_DIM * C_DIM)      // 65536 proj_w elems

typedef __bf16 bf16x8 __attribute__((ext_vector_type(8)));
typedef float  f32x4  __attribute__((ext_vector_type(4)));
typedef unsigned short u16x4v __attribute__((ext_vector_type(4)));
typedef unsigned short u16x8v __attribute__((ext_vector_type(8)));

__device__ __forceinline__ unsigned short f2bf(float f) {
    return __builtin_bit_cast(unsigned short, (__bf16)f);
}
__device__ __forceinline__ float bf2f(unsigned short u) {
    return (float)__builtin_bit_cast(__bf16, u);
}
// raw v_exp_f32 (2^x); inputs bounded so no OCML fixup needed
__device__ __forceinline__ float exp2_fast(float x) { return __builtin_amdgcn_exp2f(x); }

// async global->LDS, 16B per lane, wave-uniform LDS base (linear dest)
__device__ __forceinline__ void gload16(const unsigned short* g, unsigned short* l) {
    __builtin_amdgcn_global_load_lds(
        (const __attribute__((address_space(1))) unsigned int*)g,
        (__attribute__((address_space(3))) unsigned int*)l, 16, 0, 0);
}

// K-staging row permutation: [b5 b4 b3 b2 b1 b0] -> [b5 b3 b2 b4 b1 b0].
// Makes the S^T output registers exactly the PV B-fragment.
__device__ __forceinline__ int kperm(int r) {
    return (r & 0x23) | ((r & 0x0C) << 1) | ((r & 0x10) >> 2);
}

// ---------------------------------------------------------------------------
// Kernel 1: GroupNorm partial sums (1024 blocks) + weight f32->bf16 convert
// tail (262144 = 1024*256 elems, one per thread, coalesced).
__global__ __launch_bounds__(256) void gn_part_kernel(const float* __restrict__ x,
                                                      const float* __restrict__ qkv_w,
                                                      const float* __restrict__ proj_w,
                                                      float* __restrict__ partials,
                                                      unsigned short* __restrict__ wbf) {
    const int bg = blockIdx.x >> 6, ch = blockIdx.x & 63;
    const float4* p = (const float4*)(x + (size_t)bg * CPG * N_TOK) + ch * 512;
    float s = 0.f, ss = 0.f;
#pragma unroll
    for (int r = 0; r < 2; ++r) {
        float4 v = p[threadIdx.x + (r << 8)];
        s  += v.x + v.y + v.z + v.w;
        ss += v.x * v.x + v.y * v.y + v.z * v.z + v.w * v.w;
    }
#pragma unroll
    for (int off = 32; off > 0; off >>= 1) {
        s  += __shfl_down(s, off);
        ss += __shfl_down(ss, off);
    }
    __shared__ float ls[4], lss[4];
    const int lane = threadIdx.x & 63, wid = threadIdx.x >> 6;
    if (lane == 0) { ls[wid] = s; lss[wid] = ss; }

    // weight convert tail (no sync needed; independent outputs)
    const int widx = blockIdx.x * 256 + threadIdx.x;
    float wv = (widx < NQKVW) ? qkv_w[widx] : proj_w[widx - NQKVW];
    wbf[widx] = f2bf(wv);

    __syncthreads();
    if (threadIdx.x == 0) {
        partials[blockIdx.x * 2 + 0] = ls[0] + ls[1] + ls[2] + ls[3];
        partials[blockIdx.x * 2 + 1] = lss[0] + lss[1] + lss[2] + lss[3];
    }
}

// ---------------------------------------------------------------------------
// Kernel 1b: GroupNorm finalize + apply + transpose -> xnT bf16 [b][n][c].
__global__ __launch_bounds__(256) void xnorm_kernel(const float* __restrict__ x,
                                                    const float* __restrict__ partials,
                                                    const float* __restrict__ norm_w,
                                                    const float* __restrict__ norm_b,
                                                    unsigned short* __restrict__ xnT) {
    __shared__ unsigned short Xt[64][PSB];  // [n][c] bf16
    __shared__ float stat_s[GROUPS][2];
    const int n0 = blockIdx.x * 64;
    const int c0 = blockIdx.y * 64;
    const int b  = blockIdx.z;
    const int tid = threadIdx.x;

    // finalize GroupNorm stats from partials
    {
        const int g = tid >> 5, sub = tid & 31;
        const float* pp = partials + (((size_t)b * GROUPS + g) * 64 + sub * 2) * 2;
        float4 v = *(const float4*)pp;
        float s = v.x + v.z, ss = v.y + v.w;
#pragma unroll
        for (int off = 16; off > 0; off >>= 1) {
            s  += __shfl_down(s, off, 32);
            ss += __shfl_down(ss, off, 32);
        }
        if (sub == 0) {
            const float inv = 1.f / (float)(CPG * N_TOK);
            float mean = s * inv;
            float var  = ss * inv - mean * mean;
            stat_s[g][0] = mean;
            stat_s[g][1] = rsqrtf(var + EPS);
        }
        __syncthreads();
    }

    // read 64c x 64n (coalesced along n), normalize, transpose into LDS
#pragma unroll
    for (int r = 0; r < 4; ++r) {
        int idx = tid + (r << 8);
        int crow = idx >> 4, col4 = (idx & 15) << 2;
        int c = c0 + crow;
        int g = c >> 5;
        float ww = norm_w[c] * stat_s[g][1];
        float bb = norm_b[c] - stat_s[g][0] * ww;
        float4 v = *(const float4*)(x + ((size_t)b * C_DIM + c) * N_TOK + n0 + col4);
        Xt[col4 + 0][crow] = f2bf(v.x * ww + bb);
        Xt[col4 + 1][crow] = f2bf(v.y * ww + bb);
        Xt[col4 + 2][crow] = f2bf(v.z * ww + bb);
        Xt[col4 + 3][crow] = f2bf(v.w * ww + bb);
    }
    __syncthreads();

    // write xnT[b][n0+row][c0 + blk*8], 16B per thread
#pragma unroll
    for (int r = 0; r < 2; ++r) {
        int idx = tid + (r << 8);
        int row = idx >> 3, blk = idx & 7;
        *(u16x8v*)(xnT + ((size_t)b * N_TOK + n0 + row) * C_DIM + c0 + blk * 8) =
            *(const u16x8v*)&Xt[row][blk * 8];
    }
}

// ---------------------------------------------------------------------------
// Kernel 2: QKV GEMM, bf16 MFMA, pure-2-DMA (m97 recipe): Ws and Xs both via
// global_load_lds with XOR-swizzled source, linear LDS dest. Zero staging VALU.
__global__ __launch_bounds__(256) void qkv_gemm_kernel(
    const unsigned short* __restrict__ xnT, const unsigned short* __restrict__ wqbf,
    const float* __restrict__ qkv_b, unsigned short* __restrict__ qkvb) {
    __shared__ unsigned short Ws[64][64];   // [o][c] bf16, col-swizzled
    __shared__ unsigned short Xs[64][64];   // [n][c] bf16, col-swizzled
    const int n0 = blockIdx.x * 64;
    const int o0 = blockIdx.y * 64;
    const int b  = blockIdx.z;
    const int tid = threadIdx.x;
    const int lane = tid & 63, w = tid >> 6;
    const int lo = lane & 15, hi = lane >> 4;
    const int srow8 = lane >> 3, sblk = lane & 7;
    const int c16s = (sblk ^ srow8) * 8;    // swizzled source chunk (elements)
    int rcol[2];
#pragma unroll
    for (int c = 0; c < 2; ++c) rcol[c] = (((c * 4 + hi) ^ (lo & 7)) << 3);

    f32x4 acc[4] = {};
    for (int k0 = 0; k0 < C_DIM; k0 += 64) {
#pragma unroll
        for (int i = 0; i < 2; ++i) {
            int row = i * 32 + w * 8 + srow8;
            gload16(wqbf + (size_t)(o0 + row) * C_DIM + k0 + c16s, &Ws[i * 32 + w * 8][0]);
            gload16(xnT + ((size_t)b * N_TOK + n0 + row) * C_DIM + k0 + c16s,
                    &Xs[i * 32 + w * 8][0]);
        }
        __syncthreads();   // drains DMA
#pragma unroll
        for (int ck = 0; ck < 2; ++ck) {
            bf16x8 aw = *(const bf16x8*)&Ws[w * 16 + lo][rcol[ck]];
#pragma unroll
            for (int nb = 0; nb < 4; ++nb)
                acc[nb] = __builtin_amdgcn_mfma_f32_16x16x32_bf16(
                    aw, *(const bf16x8*)&Xs[nb * 16 + lo][rcol[ck]], acc[nb], 0, 0, 0);
        }
        __syncthreads();
    }

    const int sidx = o0 >> 8;           // 0=q, 1=k, 2=v
    const int head = (o0 >> 6) & 3;
    const int od = w * 16 + hi * 4;     // d within head (+i)
    float bias[4];
#pragma unroll
    for (int i = 0; i < 4; ++i) bias[i] = qkv_b[o0 + od + i];
    const size_t plane = (size_t)N_TOK * HD;

    if (sidx < 2) {
        const float sc = (sidx == 0) ? QK_SCALE : 1.0f;
        unsigned short* base = qkvb + ((size_t)(sidx * B_DIM + b) * HEADS + head) * plane;
#pragma unroll
        for (int nb = 0; nb < 4; ++nb) {
            int n = n0 + nb * 16 + lo;
            u16x4v o;
#pragma unroll
            for (int i = 0; i < 4; ++i) o[i] = f2bf((acc[nb][i] + bias[i]) * sc);
            *(u16x4v*)(base + (size_t)n * HD + od) = o;
        }
    } else {
        unsigned short* base = qkvb + (size_t)2 * B_DIM * HEADS * plane
                             + ((size_t)b * HEADS + head) * plane;
#pragma unroll
        for (int nb = 0; nb < 4; ++nb)
#pragma unroll
            for (int i = 0; i < 4; ++i)
                base[(size_t)(od + i) * N_TOK + n0 + nb * 16 + lo] = f2bf(acc[nb][i] + bias[i]);
    }
}

// ---------------------------------------------------------------------------
// Kernel 3: bf16 MFMA flash attention. Per-tile body identical to the proven
// round-10/13 kernel; staging now rotates FOUR LDS slots with ONE barrier per
// TWO tiles (compute-per-barrier ~2x load latency -> drain ~free).
__global__ __launch_bounds__(512, 4) void attn_kernel(const unsigned short* __restrict__ qkvb,
                                                      unsigned short* __restrict__ obuf,
                                                      float* __restrict__ rbuf) {
    const int bh = blockIdx.x & 7;            // b*HEADS + head
    const int ks = (blockIdx.x >> 3) & 3;     // key-split quarter
    const int q0 = (blockIdx.x >> 5) * QBLK;
    const size_t plane = (size_t)N_TOK * HD;
    const unsigned short* Qg  = qkvb + (size_t)bh * plane;
    const unsigned short* Kg  = qkvb + (size_t)(B_DIM * HEADS + bh) * plane;
    const unsigned short* Vtg = qkvb + (size_t)2 * B_DIM * HEADS * plane + (size_t)bh * plane;

    __shared__ unsigned short Ks[4][64][64];  // [slot][perm key row][d] (col-swizzled)
    __shared__ unsigned short Vt[4][64][64];  // [slot][d][key]          (col-swizzled)

    const int tid  = threadIdx.x;
    const int lane = tid & 63;
    const int wid  = tid >> 6;                // 0..7
    const int lo   = lane & 15;
    const int hi   = lane >> 4;

    // Q fragments: frag f covers q = q0 + wid*32 + f*16 + lo, d-chunks c*32+hi*8
    bf16x8 qf[2][2];
#pragma unroll
    for (int f = 0; f < 2; ++f)
#pragma unroll
        for (int c = 0; c < 2; ++c)
            qf[f][c] = *(const bf16x8*)(Qg + (size_t)(q0 + wid * 32 + f * 16 + lo) * HD
                                            + c * 32 + hi * 8);

    const int srow = tid >> 3, sblk = tid & 7;
    const int c16s = (sblk ^ (srow & 7)) * 8;
    const int krow = kperm(srow);
    int rcol[2];
#pragma unroll
    for (int c = 0; c < 2; ++c) rcol[c] = (((c * 4 + hi) ^ (lo & 7)) << 3);

#define STAGE_KV(sloti, kbase)                                                         \
    do {                                                                               \
        gload16(Kg + (size_t)((kbase) + krow) * HD + c16s, &Ks[sloti][wid * 8][0]);    \
        gload16(Vtg + (size_t)srow * N_TOK + (kbase) + c16s, &Vt[sloti][wid * 8][0]);  \
    } while (0)

    const int kt0 = ks * (NKT / KSPLIT), ktE = kt0 + NKT / KSPLIT;   // 16 tiles

    f32x4 acc[2][4] = {};   // acc[f][db][i] = O^T[d=db*16+hi*4+i][q of frag f]
    float m[2] = {-1e30f, -1e30f}, l[2] = {0.f, 0.f};

    // per-tile compute body (identical math to the proven kernel)
    auto compute_tile = [&](int cur) {
        // S^T = K Q^T for BOTH frags; each K fragment read once, used twice.
        f32x4 s4[2][4] = {};
        __builtin_amdgcn_s_setprio(1);
#pragma unroll
        for (int kb = 0; kb < 4; ++kb)
#pragma unroll
            for (int c = 0; c < 2; ++c) {
                bf16x8 kf = *(const bf16x8*)&Ks[cur][kb * 16 + lo][rcol[c]];
                s4[0][kb] = __builtin_amdgcn_mfma_f32_16x16x32_bf16(kf, qf[0][c], s4[0][kb], 0, 0, 0);
                s4[1][kb] = __builtin_amdgcn_mfma_f32_16x16x32_bf16(kf, qf[1][c], s4[1][kb], 0, 0, 0);
            }
        __builtin_amdgcn_s_setprio(0);

        // softmax per frag (lane-local; cross-lane only in rare rescale branch)
        bf16x8 pf[2][2];
#pragma unroll
        for (int f = 0; f < 2; ++f) {
            float r0 = fmaxf(fmaxf(fmaxf(s4[f][0][0], s4[f][0][1]), s4[f][0][2]), s4[f][0][3]);
            float r1 = fmaxf(fmaxf(fmaxf(s4[f][1][0], s4[f][1][1]), s4[f][1][2]), s4[f][1][3]);
            float r2 = fmaxf(fmaxf(fmaxf(s4[f][2][0], s4[f][2][1]), s4[f][2][2]), s4[f][2][3]);
            float r3 = fmaxf(fmaxf(fmaxf(s4[f][3][0], s4[f][3][1]), s4[f][3][2]), s4[f][3][3]);
            float rm = fmaxf(fmaxf(fmaxf(r0, r1), r2), r3);

            // defer-max (T13) with LOCAL max check
            if (__any(rm > m[f] + 8.0f)) {
                float rmx = rm;
                rmx = fmaxf(rmx, __shfl_xor(rmx, 16));
                rmx = fmaxf(rmx, __shfl_xor(rmx, 32));
                const float mn = fmaxf(m[f], rmx);
                const float fi = exp2_fast(m[f] - mn);
                m[f] = mn;
                l[f] *= fi;
#pragma unroll
                for (int db = 0; db < 4; ++db)
#pragma unroll
                    for (int i = 0; i < 4; ++i) acc[f][db][i] *= fi;
            }

            float p[4][4];
            float ps = 0.f;
#pragma unroll
            for (int kb = 0; kb < 4; ++kb)
#pragma unroll
                for (int i = 0; i < 4; ++i) {
                    p[kb][i] = exp2_fast(s4[f][kb][i] - m[f]);
                    ps += p[kb][i];
                }
            l[f] += ps;

            // pack P into PV B-fragment: pf[f][c][j] = p[2c + (j>>2)][j&3]
#pragma unroll
            for (int c = 0; c < 2; ++c)
#pragma unroll
                for (int j = 0; j < 8; ++j) pf[f][c][j] = (__bf16)p[2 * c + (j >> 2)][j & 3];
        }

        // O^T += V^T P^T for BOTH frags; each V fragment read once, used twice.
        __builtin_amdgcn_s_setprio(1);
#pragma unroll
        for (int db = 0; db < 4; ++db)
#pragma unroll
            for (int c = 0; c < 2; ++c) {
                bf16x8 vf = *(const bf16x8*)&Vt[cur][db * 16 + lo][rcol[c]];
                acc[0][db] = __builtin_amdgcn_mfma_f32_16x16x32_bf16(vf, pf[0][c], acc[0][db], 0, 0, 0);
                acc[1][db] = __builtin_amdgcn_mfma_f32_16x16x32_bf16(vf, pf[1][c], acc[1][db], 0, 0, 0);
            }
        __builtin_amdgcn_s_setprio(0);
    };

    // prologue: stage tiles kt0, kt0+1 into slots 0,1
    STAGE_KV(kt0 & 3, kt0 * 64);
    STAGE_KV((kt0 + 1) & 3, (kt0 + 1) * 64);
    __syncthreads();   // drains the DMA (vmcnt 0) + barrier

    for (int kt = kt0; kt < ktE; kt += 2) {
        // stage tiles kt+2, kt+3 into the two slots consumed before last barrier
        if (kt + 2 < ktE) {
            STAGE_KV((kt + 2) & 3, (kt + 2) * 64);
            STAGE_KV((kt + 3) & 3, (kt + 3) * 64);
        }
        compute_tile(kt & 3);
        compute_tile((kt + 1) & 3);
        __syncthreads();   // one barrier per TWO tiles; drains this wave's DMAs
    }
#undef STAGE_KV

    // epilogue per frag: normalized bf16 partial O + log-sum-exp r
#pragma unroll
    for (int f = 0; f < 2; ++f) {
        float l1 = l[f] + __shfl_xor(l[f], 16);
        float lt = l1 + __shfl_xor(l1, 32);
        const float inv = 1.f / lt;
        const int n = q0 + wid * 32 + f * 16 + lo;
        unsigned short* ob = obuf + ((size_t)(ks * 8 + bh) * N_TOK + n) * HD;
#pragma unroll
        for (int db = 0; db < 4; ++db) {
            u16x4v o;
#pragma unroll
            for (int i = 0; i < 4; ++i) o[i] = f2bf(acc[f][db][i] * inv);
            *(u16x4v*)(ob + db * 16 + hi * 4) = o;
        }
        if (hi == 0)
            rbuf[(size_t)(ks * 8 + bh) * N_TOK + n] = m[f] + __builtin_amdgcn_logf(lt);
    }
}

// ---------------------------------------------------------------------------
// Kernel 4: output projection + bias + residual, bf16 MFMA, with the K-split
// combine fused into the Hs staging. Ws staged via global_load_lds (swizzled);
// Hs reg-staged (combine math) into a PSB-padded tile.
__global__ __launch_bounds__(256) void proj_kernel(
    const unsigned short* __restrict__ obuf, const float* __restrict__ rbuf,
    const unsigned short* __restrict__ wpbf, const float* __restrict__ proj_b,
    const float* __restrict__ x, float* __restrict__ out) {
    __shared__ unsigned short Ws[64][64];   // [o][c] bf16, col-swizzled (DMA)
    __shared__ unsigned short Hs[64][PSB];  // [n][c-within-head], reg-staged
    const int n0 = blockIdx.x * 64;
    const int o0 = blockIdx.y * 64;
    const int b  = blockIdx.z;
    const int tid = threadIdx.x;
    const int lane = tid & 63, w = tid >> 6;
    const int lo = lane & 15, hi = lane >> 4;
    const int srow8 = lane >> 3, sblk = lane & 7;
    const int c16s = (sblk ^ srow8) * 8;
    int rcol[2];
#pragma unroll
    for (int c = 0; c < 2; ++c) rcol[c] = (((c * 4 + hi) ^ (lo & 7)) << 3);

    f32x4 acc[4] = {};
    for (int k0 = 0; k0 < C_DIM; k0 += 64) {
        // Ws via DMA (2 instrs / wave)
#pragma unroll
        for (int i = 0; i < 2; ++i) {
            int row = i * 32 + w * 8 + srow8;
            gload16(wpbf + (size_t)(o0 + row) * C_DIM + k0 + c16s, &Ws[i * 32 + w * 8][0]);
        }
        // stage h[n][k0..k0+64): head = k0>>6; combine the 4 K-split partials
        {
            const int head = k0 >> 6;
            const int bh = b * HEADS + head;
#pragma unroll
            for (int r = 0; r < 2; ++r) {
                int idx = tid + (r << 8);
                int row = idx >> 3, blk = idx & 7;   // n-row in tile, 8-d chunk
                int n = n0 + row;
                float rr[KSPLIT], M = -1e30f;
#pragma unroll
                for (int k = 0; k < KSPLIT; ++k) {
                    rr[k] = rbuf[(size_t)(k * 8 + bh) * N_TOK + n];
                    M = fmaxf(M, rr[k]);
                }
                float wk[KSPLIT], tot = 0.f;
#pragma unroll
                for (int k = 0; k < KSPLIT; ++k) { wk[k] = exp2_fast(rr[k] - M); tot += wk[k]; }
                const float inv = 1.f / tot;
                float a[8] = {};
#pragma unroll
                for (int k = 0; k < KSPLIT; ++k) {
                    u16x8v v = *(const u16x8v*)(obuf
                        + ((size_t)(k * 8 + bh) * N_TOK + n) * HD + blk * 8);
#pragma unroll
                    for (int j = 0; j < 8; ++j) a[j] += wk[k] * bf2f(v[j]);
                }
                u16x8v o;
#pragma unroll
                for (int j = 0; j < 8; ++j) o[j] = f2bf(a[j] * inv);
                *(u16x8v*)&Hs[row][blk * 8] = o;
            }
        }
        __syncthreads();   // drains DMA (vmcnt) + ds_writes (lgkm)
#pragma unroll
        for (int ck = 0; ck < 2; ++ck) {
            bf16x8 aw = *(const bf16x8*)&Ws[w * 16 + lo][rcol[ck]];
#pragma unroll
            for (int nb = 0; nb < 4; ++nb)
                acc[nb] = __builtin_amdgcn_mfma_f32_16x16x32_bf16(
                    aw, *(const bf16x8*)&Hs[nb * 16 + lo][ck * 32 + hi * 8], acc[nb], 0, 0, 0);
        }
        __syncthreads();
    }

#pragma unroll
    for (int nb = 0; nb < 4; ++nb) {
#pragma unroll
        for (int i = 0; i < 4; ++i) {
            int o = o0 + w * 16 + hi * 4 + i;
            size_t addr = ((size_t)b * C_DIM + o) * N_TOK + n0 + nb * 16 + lo;
            out[addr] = acc[nb][i] + proj_b[o] + x[addr];
        }
    }
}

// ---------------------------------------------------------------------------
extern "C" void kernel_launch(void* const* d_in, const int* in_sizes, int n_in,
                              void* d_out, int out_size, void* d_ws, size_t ws_size,
                              hipStream_t stream) {
    const float* x      = (const float*)d_in[0];
    const float* norm_w = (const float*)d_in[1];
    const float* norm_b = (const float*)d_in[2];
    const float* qkv_w  = (const float*)d_in[3];
    const float* qkv_b  = (const float*)d_in[4];
    const float* proj_w = (const float*)d_in[5];
    const float* proj_b = (const float*)d_in[6];
    float* out = (float*)d_out;

    // ws: partials f32[2048] (8KB) | wbf u16[262144] (512KB) | xnT bf16 (4.2MB)
    //   | qkvb bf16 (12.6MB) | obuf bf16 [4][8][N][HD] (16.8MB)
    //   | rbuf f32 [4][8][N] (512KB)  ~= 34.6MB
    float* partials = (float*)d_ws;
    unsigned short* wbf = (unsigned short*)(partials + 2048);
    unsigned short* xnT = wbf + (NQKVW + NPROJW);
    unsigned short* qkvb = xnT + (size_t)B_DIM * N_TOK * C_DIM;
    unsigned short* obuf = qkvb + (size_t)3 * B_DIM * HEADS * N_TOK * HD;
    float* rbuf = (float*)(obuf + (size_t)KSPLIT * B_DIM * HEADS * N_TOK * HD);
    const unsigned short* wqbf = wbf;
    const unsigned short* wpbf = wbf + NQKVW;

    gn_part_kernel<<<B_DIM * GROUPS * 64, 256, 0, stream>>>(x, qkv_w, proj_w, partials, wbf);
    xnorm_kernel<<<dim3(N_TOK / 64, C_DIM / 64, B_DIM), 256, 0, stream>>>(
        x, partials, norm_w, norm_b, xnT);
    qkv_gemm_kernel<<<dim3(N_TOK / 64, 3 * C_DIM / 64, B_DIM), 256, 0, stream>>>(
        xnT, wqbf, qkv_b, qkvb);
    attn_kernel<<<(N_TOK / QBLK) * B_DIM * HEADS * KSPLIT, 512, 0, stream>>>(qkvb, obuf, rbuf);
    proj_kernel<<<dim3(N_TOK / 64, C_DIM / 64, B_DIM), 256, 0, stream>>>(
        obuf, rbuf, wpbf, proj_b, x, out);
}

// Round 18
// 78.143 us; speedup vs baseline: 1.2501x; 1.0088x over previous
//
#include <hip/hip_runtime.h>
#include <math.h>

#define B_DIM 2
#define C_DIM 256
#define N_TOK 4096      // 16*16*16
#define HEADS 4
#define HD 64
#define GROUPS 8
#define CPG (C_DIM / GROUPS)   // 32
#define EPS 1e-5f
#define PSB 72          // padded bf16 LDS row stride (reg-staged tiles)
#define QK_SCALE 0.180336880f  // 0.125 * log2(e), folded into Q
#define KSPLIT 4
#define NKT (N_TOK / 64)       // 64 key tiles total
#define QBLK 256               // queries per attention block (8 waves x 2 frags x 16 q)
#define NQKVW (3 * C_DIM * C_DIM)   // 196608 qkv_w elems
#define NPROJW (C_DIM * C_DIM)      // 65536 proj_w elems

typedef __bf16 bf16x8 __attribute__((ext_vector_type(8)));
typedef float  f32x4  __attribute__((ext_vector_type(4)));
typedef unsigned short u16x4v __attribute__((ext_vector_type(4)));
typedef unsigned short u16x8v __attribute__((ext_vector_type(8)));

__device__ __forceinline__ unsigned short f2bf(float f) {
    return __builtin_bit_cast(unsigned short, (__bf16)f);
}
__device__ __forceinline__ float bf2f(unsigned short u) {
    return (float)__builtin_bit_cast(__bf16, u);
}
// raw v_exp_f32 (2^x); inputs bounded so no OCML fixup needed
__device__ __forceinline__ float exp2_fast(float x) { return __builtin_amdgcn_exp2f(x); }

// async global->LDS, 16B per lane, wave-uniform LDS base (linear dest)
__device__ __forceinline__ void gload16(const unsigned short* g, unsigned short* l) {
    __builtin_amdgcn_global_load_lds(
        (const __attribute__((address_space(1))) unsigned int*)g,
        (__attribute__((address_space(3))) unsigned int*)l, 16, 0, 0);
}

// K-staging row permutation: [b5 b4 b3 b2 b1 b0] -> [b5 b3 b2 b4 b1 b0].
// Makes the S^T output registers exactly the PV B-fragment.
__device__ __forceinline__ int kperm(int r) {
    return (r & 0x23) | ((r & 0x0C) << 1) | ((r & 0x10) >> 2);
}

// ---------------------------------------------------------------------------
// Kernel 1: GroupNorm partial sums (1024 blocks) + weight f32->bf16 convert
// tail (262144 = 1024*256 elems, one per thread, coalesced).
__global__ __launch_bounds__(256) void gn_part_kernel(const float* __restrict__ x,
                                                      const float* __restrict__ qkv_w,
                                                      const float* __restrict__ proj_w,
                                                      float* __restrict__ partials,
                                                      unsigned short* __restrict__ wbf) {
    const int bg = blockIdx.x >> 6, ch = blockIdx.x & 63;
    const float4* p = (const float4*)(x + (size_t)bg * CPG * N_TOK) + ch * 512;
    float s = 0.f, ss = 0.f;
#pragma unroll
    for (int r = 0; r < 2; ++r) {
        float4 v = p[threadIdx.x + (r << 8)];
        s  += v.x + v.y + v.z + v.w;
        ss += v.x * v.x + v.y * v.y + v.z * v.z + v.w * v.w;
    }
#pragma unroll
    for (int off = 32; off > 0; off >>= 1) {
        s  += __shfl_down(s, off);
        ss += __shfl_down(ss, off);
    }
    __shared__ float ls[4], lss[4];
    const int lane = threadIdx.x & 63, wid = threadIdx.x >> 6;
    if (lane == 0) { ls[wid] = s; lss[wid] = ss; }

    // weight convert tail (no sync needed; independent outputs)
    const int widx = blockIdx.x * 256 + threadIdx.x;
    float wv = (widx < NQKVW) ? qkv_w[widx] : proj_w[widx - NQKVW];
    wbf[widx] = f2bf(wv);

    __syncthreads();
    if (threadIdx.x == 0) {
        partials[blockIdx.x * 2 + 0] = ls[0] + ls[1] + ls[2] + ls[3];
        partials[blockIdx.x * 2 + 1] = lss[0] + lss[1] + lss[2] + lss[3];
    }
}

// ---------------------------------------------------------------------------
// Kernel 1b: GroupNorm finalize + apply + transpose -> xnT bf16 [b][n][c].
__global__ __launch_bounds__(256) void xnorm_kernel(const float* __restrict__ x,
                                                    const float* __restrict__ partials,
                                                    const float* __restrict__ norm_w,
                                                    const float* __restrict__ norm_b,
                                                    unsigned short* __restrict__ xnT) {
    __shared__ unsigned short Xt[64][PSB];  // [n][c] bf16
    __shared__ float stat_s[GROUPS][2];
    const int n0 = blockIdx.x * 64;
    const int c0 = blockIdx.y * 64;
    const int b  = blockIdx.z;
    const int tid = threadIdx.x;

    // finalize GroupNorm stats from partials
    {
        const int g = tid >> 5, sub = tid & 31;
        const float* pp = partials + (((size_t)b * GROUPS + g) * 64 + sub * 2) * 2;
        float4 v = *(const float4*)pp;
        float s = v.x + v.z, ss = v.y + v.w;
#pragma unroll
        for (int off = 16; off > 0; off >>= 1) {
            s  += __shfl_down(s, off, 32);
            ss += __shfl_down(ss, off, 32);
        }
        if (sub == 0) {
            const float inv = 1.f / (float)(CPG * N_TOK);
            float mean = s * inv;
            float var  = ss * inv - mean * mean;
            stat_s[g][0] = mean;
            stat_s[g][1] = rsqrtf(var + EPS);
        }
        __syncthreads();
    }

    // read 64c x 64n (coalesced along n), normalize, transpose into LDS
#pragma unroll
    for (int r = 0; r < 4; ++r) {
        int idx = tid + (r << 8);
        int crow = idx >> 4, col4 = (idx & 15) << 2;
        int c = c0 + crow;
        int g = c >> 5;
        float ww = norm_w[c] * stat_s[g][1];
        float bb = norm_b[c] - stat_s[g][0] * ww;
        float4 v = *(const float4*)(x + ((size_t)b * C_DIM + c) * N_TOK + n0 + col4);
        Xt[col4 + 0][crow] = f2bf(v.x * ww + bb);
        Xt[col4 + 1][crow] = f2bf(v.y * ww + bb);
        Xt[col4 + 2][crow] = f2bf(v.z * ww + bb);
        Xt[col4 + 3][crow] = f2bf(v.w * ww + bb);
    }
    __syncthreads();

    // write xnT[b][n0+row][c0 + blk*8], 16B per thread
#pragma unroll
    for (int r = 0; r < 2; ++r) {
        int idx = tid + (r << 8);
        int row = idx >> 3, blk = idx & 7;
        *(u16x8v*)(xnT + ((size_t)b * N_TOK + n0 + row) * C_DIM + c0 + blk * 8) =
            *(const u16x8v*)&Xt[row][blk * 8];
    }
}

// ---------------------------------------------------------------------------
// Kernel 2: QKV GEMM, bf16 MFMA, pure-2-DMA, o-tile 256 (512 threads, 8 waves,
// 2 o-frags/wave). xnT re-read drops 12x -> 3x. sidx uniform per block.
__global__ __launch_bounds__(512) void qkv_gemm_kernel(
    const unsigned short* __restrict__ xnT, const unsigned short* __restrict__ wqbf,
    const float* __restrict__ qkv_b, unsigned short* __restrict__ qkvb) {
    __shared__ unsigned short Ws[256][64];  // [o][c] bf16, col-swizzled (32KB)
    __shared__ unsigned short Xs[64][64];   // [n][c] bf16, col-swizzled (8KB)
    const int n0 = blockIdx.x * 64;
    const int o0 = blockIdx.y * 256;        // 0 | 256 | 512  (q | k | v)
    const int b  = blockIdx.z;
    const int tid = threadIdx.x;
    const int lane = tid & 63, w = tid >> 6;
    const int lo = lane & 15, hi = lane >> 4;
    const int tsrow = tid >> 3, tsblk = tid & 7;       // 512-thread staging map
    const int tc16s = (tsblk ^ (tsrow & 7)) * 8;       // swizzled source chunk
    int rcol[2];
#pragma unroll
    for (int c = 0; c < 2; ++c) rcol[c] = (((c * 4 + hi) ^ (lo & 7)) << 3);

    f32x4 acc[2][4] = {};   // acc[f][nb]: o = o0+w*32+f*16+hi*4+i, n = n0+nb*16+lo
    for (int k0 = 0; k0 < C_DIM; k0 += 64) {
        // Ws: 4 DMA issues cover 256 rows (issue i -> rows i*64 + wave-local 8)
#pragma unroll
        for (int i = 0; i < 4; ++i)
            gload16(wqbf + (size_t)(o0 + i * 64 + tsrow) * C_DIM + k0 + tc16s,
                    &Ws[i * 64 + w * 8][0]);
        // Xs: 1 DMA issue covers 64 rows
        gload16(xnT + ((size_t)b * N_TOK + n0 + tsrow) * C_DIM + k0 + tc16s,
                &Xs[w * 8][0]);
        __syncthreads();   // drains DMA
#pragma unroll
        for (int ck = 0; ck < 2; ++ck) {
            bf16x8 aw[2];
#pragma unroll
            for (int f = 0; f < 2; ++f)
                aw[f] = *(const bf16x8*)&Ws[w * 32 + f * 16 + lo][rcol[ck]];
#pragma unroll
            for (int nb = 0; nb < 4; ++nb) {
                bf16x8 xb = *(const bf16x8*)&Xs[nb * 16 + lo][rcol[ck]];
                acc[0][nb] = __builtin_amdgcn_mfma_f32_16x16x32_bf16(aw[0], xb, acc[0][nb], 0, 0, 0);
                acc[1][nb] = __builtin_amdgcn_mfma_f32_16x16x32_bf16(aw[1], xb, acc[1][nb], 0, 0, 0);
            }
        }
        __syncthreads();
    }

    const int sidx = o0 >> 8;           // uniform per block: 0=q, 1=k, 2=v
    const size_t plane = (size_t)N_TOK * HD;
#pragma unroll
    for (int f = 0; f < 2; ++f) {
        const int ob = w * 32 + f * 16;          // o within tile (16-aligned)
        const int head = (ob >> 6) & 3;
        const int od = (ob & 63) + hi * 4;       // d within head (+i)
        float bias[4];
#pragma unroll
        for (int i = 0; i < 4; ++i) bias[i] = qkv_b[o0 + ob + hi * 4 + i];

        if (sidx < 2) {
            const float sc = (sidx == 0) ? QK_SCALE : 1.0f;
            unsigned short* base = qkvb + ((size_t)(sidx * B_DIM + b) * HEADS + head) * plane;
#pragma unroll
            for (int nb = 0; nb < 4; ++nb) {
                int n = n0 + nb * 16 + lo;
                u16x4v o;
#pragma unroll
                for (int i = 0; i < 4; ++i) o[i] = f2bf((acc[f][nb][i] + bias[i]) * sc);
                *(u16x4v*)(base + (size_t)n * HD + od) = o;
            }
        } else {
            unsigned short* base = qkvb + (size_t)2 * B_DIM * HEADS * plane
                                 + ((size_t)b * HEADS + head) * plane;
#pragma unroll
            for (int nb = 0; nb < 4; ++nb) {
                int n = n0 + nb * 16 + lo;
#pragma unroll
                for (int i = 0; i < 4; ++i)
                    base[(size_t)(od + i) * N_TOK + n] = f2bf(acc[f][nb][i] + bias[i]);
            }
        }
    }
}

// ---------------------------------------------------------------------------
// Kernel 3: bf16 MFMA flash attention (round-17 proven: 4 LDS slots, one
// barrier per two tiles; per-tile body identical to round-10/13).
__global__ __launch_bounds__(512, 4) void attn_kernel(const unsigned short* __restrict__ qkvb,
                                                      unsigned short* __restrict__ obuf,
                                                      float* __restrict__ rbuf) {
    const int bh = blockIdx.x & 7;            // b*HEADS + head
    const int ks = (blockIdx.x >> 3) & 3;     // key-split quarter
    const int q0 = (blockIdx.x >> 5) * QBLK;
    const size_t plane = (size_t)N_TOK * HD;
    const unsigned short* Qg  = qkvb + (size_t)bh * plane;
    const unsigned short* Kg  = qkvb + (size_t)(B_DIM * HEADS + bh) * plane;
    const unsigned short* Vtg = qkvb + (size_t)2 * B_DIM * HEADS * plane + (size_t)bh * plane;

    __shared__ unsigned short Ks[4][64][64];  // [slot][perm key row][d] (col-swizzled)
    __shared__ unsigned short Vt[4][64][64];  // [slot][d][key]          (col-swizzled)

    const int tid  = threadIdx.x;
    const int lane = tid & 63;
    const int wid  = tid >> 6;                // 0..7
    const int lo   = lane & 15;
    const int hi   = lane >> 4;

    // Q fragments: frag f covers q = q0 + wid*32 + f*16 + lo, d-chunks c*32+hi*8
    bf16x8 qf[2][2];
#pragma unroll
    for (int f = 0; f < 2; ++f)
#pragma unroll
        for (int c = 0; c < 2; ++c)
            qf[f][c] = *(const bf16x8*)(Qg + (size_t)(q0 + wid * 32 + f * 16 + lo) * HD
                                            + c * 32 + hi * 8);

    const int srow = tid >> 3, sblk = tid & 7;
    const int c16s = (sblk ^ (srow & 7)) * 8;
    const int krow = kperm(srow);
    int rcol[2];
#pragma unroll
    for (int c = 0; c < 2; ++c) rcol[c] = (((c * 4 + hi) ^ (lo & 7)) << 3);

#define STAGE_KV(sloti, kbase)                                                         \
    do {                                                                               \
        gload16(Kg + (size_t)((kbase) + krow) * HD + c16s, &Ks[sloti][wid * 8][0]);    \
        gload16(Vtg + (size_t)srow * N_TOK + (kbase) + c16s, &Vt[sloti][wid * 8][0]);  \
    } while (0)

    const int kt0 = ks * (NKT / KSPLIT), ktE = kt0 + NKT / KSPLIT;   // 16 tiles

    f32x4 acc[2][4] = {};   // acc[f][db][i] = O^T[d=db*16+hi*4+i][q of frag f]
    float m[2] = {-1e30f, -1e30f}, l[2] = {0.f, 0.f};

    // per-tile compute body (identical math to the proven kernel)
    auto compute_tile = [&](int cur) {
        // S^T = K Q^T for BOTH frags; each K fragment read once, used twice.
        f32x4 s4[2][4] = {};
        __builtin_amdgcn_s_setprio(1);
#pragma unroll
        for (int kb = 0; kb < 4; ++kb)
#pragma unroll
            for (int c = 0; c < 2; ++c) {
                bf16x8 kf = *(const bf16x8*)&Ks[cur][kb * 16 + lo][rcol[c]];
                s4[0][kb] = __builtin_amdgcn_mfma_f32_16x16x32_bf16(kf, qf[0][c], s4[0][kb], 0, 0, 0);
                s4[1][kb] = __builtin_amdgcn_mfma_f32_16x16x32_bf16(kf, qf[1][c], s4[1][kb], 0, 0, 0);
            }
        __builtin_amdgcn_s_setprio(0);

        // softmax per frag (lane-local; cross-lane only in rare rescale branch)
        bf16x8 pf[2][2];
#pragma unroll
        for (int f = 0; f < 2; ++f) {
            float r0 = fmaxf(fmaxf(fmaxf(s4[f][0][0], s4[f][0][1]), s4[f][0][2]), s4[f][0][3]);
            float r1 = fmaxf(fmaxf(fmaxf(s4[f][1][0], s4[f][1][1]), s4[f][1][2]), s4[f][1][3]);
            float r2 = fmaxf(fmaxf(fmaxf(s4[f][2][0], s4[f][2][1]), s4[f][2][2]), s4[f][2][3]);
            float r3 = fmaxf(fmaxf(fmaxf(s4[f][3][0], s4[f][3][1]), s4[f][3][2]), s4[f][3][3]);
            float rm = fmaxf(fmaxf(fmaxf(r0, r1), r2), r3);

            // defer-max (T13) with LOCAL max check
            if (__any(rm > m[f] + 8.0f)) {
                float rmx = rm;
                rmx = fmaxf(rmx, __shfl_xor(rmx, 16));
                rmx = fmaxf(rmx, __shfl_xor(rmx, 32));
                const float mn = fmaxf(m[f], rmx);
                const float fi = exp2_fast(m[f] - mn);
                m[f] = mn;
                l[f] *= fi;
#pragma unroll
                for (int db = 0; db < 4; ++db)
#pragma unroll
                    for (int i = 0; i < 4; ++i) acc[f][db][i] *= fi;
            }

            float p[4][4];
            float ps = 0.f;
#pragma unroll
            for (int kb = 0; kb < 4; ++kb)
#pragma unroll
                for (int i = 0; i < 4; ++i) {
                    p[kb][i] = exp2_fast(s4[f][kb][i] - m[f]);
                    ps += p[kb][i];
                }
            l[f] += ps;

            // pack P into PV B-fragment: pf[f][c][j] = p[2c + (j>>2)][j&3]
#pragma unroll
            for (int c = 0; c < 2; ++c)
#pragma unroll
                for (int j = 0; j < 8; ++j) pf[f][c][j] = (__bf16)p[2 * c + (j >> 2)][j & 3];
        }

        // O^T += V^T P^T for BOTH frags; each V fragment read once, used twice.
        __builtin_amdgcn_s_setprio(1);
#pragma unroll
        for (int db = 0; db < 4; ++db)
#pragma unroll
            for (int c = 0; c < 2; ++c) {
                bf16x8 vf = *(const bf16x8*)&Vt[cur][db * 16 + lo][rcol[c]];
                acc[0][db] = __builtin_amdgcn_mfma_f32_16x16x32_bf16(vf, pf[0][c], acc[0][db], 0, 0, 0);
                acc[1][db] = __builtin_amdgcn_mfma_f32_16x16x32_bf16(vf, pf[1][c], acc[1][db], 0, 0, 0);
            }
        __builtin_amdgcn_s_setprio(0);
    };

    // prologue: stage tiles kt0, kt0+1 into slots 0,1
    STAGE_KV(kt0 & 3, kt0 * 64);
    STAGE_KV((kt0 + 1) & 3, (kt0 + 1) * 64);
    __syncthreads();   // drains the DMA (vmcnt 0) + barrier

    for (int kt = kt0; kt < ktE; kt += 2) {
        // stage tiles kt+2, kt+3 into the two slots consumed before last barrier
        if (kt + 2 < ktE) {
            STAGE_KV((kt + 2) & 3, (kt + 2) * 64);
            STAGE_KV((kt + 3) & 3, (kt + 3) * 64);
        }
        compute_tile(kt & 3);
        compute_tile((kt + 1) & 3);
        __syncthreads();   // one barrier per TWO tiles; drains this wave's DMAs
    }
#undef STAGE_KV

    // epilogue per frag: normalized bf16 partial O + log-sum-exp r
#pragma unroll
    for (int f = 0; f < 2; ++f) {
        float l1 = l[f] + __shfl_xor(l[f], 16);
        float lt = l1 + __shfl_xor(l1, 32);
        const float inv = 1.f / lt;
        const int n = q0 + wid * 32 + f * 16 + lo;
        unsigned short* ob = obuf + ((size_t)(ks * 8 + bh) * N_TOK + n) * HD;
#pragma unroll
        for (int db = 0; db < 4; ++db) {
            u16x4v o;
#pragma unroll
            for (int i = 0; i < 4; ++i) o[i] = f2bf(acc[f][db][i] * inv);
            *(u16x4v*)(ob + db * 16 + hi * 4) = o;
        }
        if (hi == 0)
            rbuf[(size_t)(ks * 8 + bh) * N_TOK + n] = m[f] + __builtin_amdgcn_logf(lt);
    }
}

// ---------------------------------------------------------------------------
// Kernel 4: output projection + bias + residual, bf16 MFMA, combine fused into
// Hs staging. o-tile 128 (512 threads, 8 waves x 16 o-rows): obuf/combine
// redundancy halves vs o-tile 64.
__global__ __launch_bounds__(512) void proj_kernel(
    const unsigned short* __restrict__ obuf, const float* __restrict__ rbuf,
    const unsigned short* __restrict__ wpbf, const float* __restrict__ proj_b,
    const float* __restrict__ x, float* __restrict__ out) {
    __shared__ unsigned short Ws[128][64];  // [o][c] bf16, col-swizzled (16KB, DMA)
    __shared__ unsigned short Hs[64][PSB];  // [n][c-within-head], reg-staged
    const int n0 = blockIdx.x * 64;
    const int o0 = blockIdx.y * 128;
    const int b  = blockIdx.z;
    const int tid = threadIdx.x;
    const int lane = tid & 63, w = tid >> 6;
    const int lo = lane & 15, hi = lane >> 4;
    const int tsrow = tid >> 3, tsblk = tid & 7;
    const int tc16s = (tsblk ^ (tsrow & 7)) * 8;
    int rcol[2];
#pragma unroll
    for (int c = 0; c < 2; ++c) rcol[c] = (((c * 4 + hi) ^ (lo & 7)) << 3);

    f32x4 acc[4] = {};      // o = o0 + w*16 + hi*4 + i, n = n0 + nb*16 + lo
    for (int k0 = 0; k0 < C_DIM; k0 += 64) {
        // Ws via DMA: 2 issues cover 128 rows
#pragma unroll
        for (int i = 0; i < 2; ++i)
            gload16(wpbf + (size_t)(o0 + i * 64 + tsrow) * C_DIM + k0 + tc16s,
                    &Ws[i * 64 + w * 8][0]);
        // stage h[n][k0..k0+64): head = k0>>6; combine the 4 K-split partials
        // 512 threads cover 64 rows x 8 chunks in ONE pass.
        {
            const int head = k0 >> 6;
            const int bh = b * HEADS + head;
            int row = tsrow, blk = tsblk;
            int n = n0 + row;
            float rr[KSPLIT], M = -1e30f;
#pragma unroll
            for (int k = 0; k < KSPLIT; ++k) {
                rr[k] = rbuf[(size_t)(k * 8 + bh) * N_TOK + n];
                M = fmaxf(M, rr[k]);
            }
            float wk[KSPLIT], tot = 0.f;
#pragma unroll
            for (int k = 0; k < KSPLIT; ++k) { wk[k] = exp2_fast(rr[k] - M); tot += wk[k]; }
            const float inv = 1.f / tot;
            float a[8] = {};
#pragma unroll
            for (int k = 0; k < KSPLIT; ++k) {
                u16x8v v = *(const u16x8v*)(obuf
                    + ((size_t)(k * 8 + bh) * N_TOK + n) * HD + blk * 8);
#pragma unroll
                for (int j = 0; j < 8; ++j) a[j] += wk[k] * bf2f(v[j]);
            }
            u16x8v o;
#pragma unroll
            for (int j = 0; j < 8; ++j) o[j] = f2bf(a[j] * inv);
            *(u16x8v*)&Hs[row][blk * 8] = o;
        }
        __syncthreads();   // drains DMA (vmcnt) + ds_writes (lgkm)
#pragma unroll
        for (int ck = 0; ck < 2; ++ck) {
            bf16x8 aw = *(const bf16x8*)&Ws[w * 16 + lo][rcol[ck]];
#pragma unroll
            for (int nb = 0; nb < 4; ++nb)
                acc[nb] = __builtin_amdgcn_mfma_f32_16x16x32_bf16(
                    aw, *(const bf16x8*)&Hs[nb * 16 + lo][ck * 32 + hi * 8], acc[nb], 0, 0, 0);
        }
        __syncthreads();
    }

#pragma unroll
    for (int nb = 0; nb < 4; ++nb) {
#pragma unroll
        for (int i = 0; i < 4; ++i) {
            int o = o0 + w * 16 + hi * 4 + i;
            size_t addr = ((size_t)b * C_DIM + o) * N_TOK + n0 + nb * 16 + lo;
            out[addr] = acc[nb][i] + proj_b[o] + x[addr];
        }
    }
}

// ---------------------------------------------------------------------------
extern "C" void kernel_launch(void* const* d_in, const int* in_sizes, int n_in,
                              void* d_out, int out_size, void* d_ws, size_t ws_size,
                              hipStream_t stream) {
    const float* x      = (const float*)d_in[0];
    const float* norm_w = (const float*)d_in[1];
    const float* norm_b = (const float*)d_in[2];
    const float* qkv_w  = (const float*)d_in[3];
    const float* qkv_b  = (const float*)d_in[4];
    const float* proj_w = (const float*)d_in[5];
    const float* proj_b = (const float*)d_in[6];
    float* out = (float*)d_out;

    // ws: partials f32[2048] (8KB) | wbf u16[262144] (512KB) | xnT bf16 (4.2MB)
    //   | qkvb bf16 (12.6MB) | obuf bf16 [4][8][N][HD] (16.8MB)
    //   | rbuf f32 [4][8][N] (512KB)  ~= 34.6MB
    float* partials = (float*)d_ws;
    unsigned short* wbf = (unsigned short*)(partials + 2048);
    unsigned short* xnT = wbf + (NQKVW + NPROJW);
    unsigned short* qkvb = xnT + (size_t)B_DIM * N_TOK * C_DIM;
    unsigned short* obuf = qkvb + (size_t)3 * B_DIM * HEADS * N_TOK * HD;
    float* rbuf = (float*)(obuf + (size_t)KSPLIT * B_DIM * HEADS * N_TOK * HD);
    const unsigned short* wqbf = wbf;
    const unsigned short* wpbf = wbf + NQKVW;

    gn_part_kernel<<<B_DIM * GROUPS * 64, 256, 0, stream>>>(x, qkv_w, proj_w, partials, wbf);
    xnorm_kernel<<<dim3(N_TOK / 64, C_DIM / 64, B_DIM), 256, 0, stream>>>(
        x, partials, norm_w, norm_b, xnT);
    qkv_gemm_kernel<<<dim3(N_TOK / 64, 3, B_DIM), 512, 0, stream>>>(
        xnT, wqbf, qkv_b, qkvb);
    attn_kernel<<<(N_TOK / QBLK) * B_DIM * HEADS * KSPLIT, 512, 0, stream>>>(qkvb, obuf, rbuf);
    proj_kernel<<<dim3(N_TOK / 64, 2, B_DIM), 512, 0, stream>>>(
        obuf, rbuf, wpbf, proj_b, x, out);
}

// Round 19
// 77.951 us; speedup vs baseline: 1.2532x; 1.0025x over previous
//
#include <hip/hip_runtime.h>
#include <math.h>

#define B_DIM 2
#define C_DIM 256
#define N_TOK 4096      // 16*16*16
#define HEADS 4
#define HD 64
#define GROUPS 8
#define CPG (C_DIM / GROUPS)   // 32
#define EPS 1e-5f
#define PSB 72          // padded bf16 LDS row stride (reg-staged tiles)
#define QK_SCALE 0.180336880f  // 0.125 * log2(e), folded into Q
#define KSPLIT 4
#define NKT (N_TOK / 64)       // 64 key tiles total
#define QBLK 256               // queries per attention block (8 waves x 2 frags x 16 q)
#define NQKVW (3 * C_DIM * C_DIM)   // 196608 qkv_w elems
#define NPROJW (C_DIM * C_DIM)      // 65536 proj_w elems

typedef __bf16 bf16x8 __attribute__((ext_vector_type(8)));
typedef float  f32x4  __attribute__((ext_vector_type(4)));
typedef unsigned short u16x4v __attribute__((ext_vector_type(4)));
typedef unsigned short u16x8v __attribute__((ext_vector_type(8)));

__device__ __forceinline__ unsigned short f2bf(float f) {
    return __builtin_bit_cast(unsigned short, (__bf16)f);
}
__device__ __forceinline__ float bf2f(unsigned short u) {
    return (float)__builtin_bit_cast(__bf16, u);
}
// raw v_exp_f32 (2^x); inputs bounded so no OCML fixup needed
__device__ __forceinline__ float exp2_fast(float x) { return __builtin_amdgcn_exp2f(x); }

// async global->LDS, 16B per lane, wave-uniform LDS base (linear dest)
__device__ __forceinline__ void gload16(const unsigned short* g, unsigned short* l) {
    __builtin_amdgcn_global_load_lds(
        (const __attribute__((address_space(1))) unsigned int*)g,
        (__attribute__((address_space(3))) unsigned int*)l, 16, 0, 0);
}

// K-staging row permutation: [b5 b4 b3 b2 b1 b0] -> [b5 b3 b2 b4 b1 b0].
// Makes the S^T output registers exactly the PV B-fragment.
__device__ __forceinline__ int kperm(int r) {
    return (r & 0x23) | ((r & 0x0C) << 1) | ((r & 0x10) >> 2);
}

// ---------------------------------------------------------------------------
// Kernel 1: GroupNorm partial sums (1024 blocks) + weight f32->bf16 convert
// tail (262144 = 1024*256 elems, one per thread, coalesced).
__global__ __launch_bounds__(256) void gn_part_kernel(const float* __restrict__ x,
                                                      const float* __restrict__ qkv_w,
                                                      const float* __restrict__ proj_w,
                                                      float* __restrict__ partials,
                                                      unsigned short* __restrict__ wbf) {
    const int bg = blockIdx.x >> 6, ch = blockIdx.x & 63;
    const float4* p = (const float4*)(x + (size_t)bg * CPG * N_TOK) + ch * 512;
    float s = 0.f, ss = 0.f;
#pragma unroll
    for (int r = 0; r < 2; ++r) {
        float4 v = p[threadIdx.x + (r << 8)];
        s  += v.x + v.y + v.z + v.w;
        ss += v.x * v.x + v.y * v.y + v.z * v.z + v.w * v.w;
    }
#pragma unroll
    for (int off = 32; off > 0; off >>= 1) {
        s  += __shfl_down(s, off);
        ss += __shfl_down(ss, off);
    }
    __shared__ float ls[4], lss[4];
    const int lane = threadIdx.x & 63, wid = threadIdx.x >> 6;
    if (lane == 0) { ls[wid] = s; lss[wid] = ss; }

    // weight convert tail (no sync needed; independent outputs)
    const int widx = blockIdx.x * 256 + threadIdx.x;
    float wv = (widx < NQKVW) ? qkv_w[widx] : proj_w[widx - NQKVW];
    wbf[widx] = f2bf(wv);

    __syncthreads();
    if (threadIdx.x == 0) {
        partials[blockIdx.x * 2 + 0] = ls[0] + ls[1] + ls[2] + ls[3];
        partials[blockIdx.x * 2 + 1] = lss[0] + lss[1] + lss[2] + lss[3];
    }
}

// ---------------------------------------------------------------------------
// Kernel 1b: GroupNorm finalize + apply + transpose -> xnT bf16 [b][n][c].
__global__ __launch_bounds__(256) void xnorm_kernel(const float* __restrict__ x,
                                                    const float* __restrict__ partials,
                                                    const float* __restrict__ norm_w,
                                                    const float* __restrict__ norm_b,
                                                    unsigned short* __restrict__ xnT) {
    __shared__ unsigned short Xt[64][PSB];  // [n][c] bf16
    __shared__ float stat_s[GROUPS][2];
    const int n0 = blockIdx.x * 64;
    const int c0 = blockIdx.y * 64;
    const int b  = blockIdx.z;
    const int tid = threadIdx.x;

    // finalize GroupNorm stats from partials
    {
        const int g = tid >> 5, sub = tid & 31;
        const float* pp = partials + (((size_t)b * GROUPS + g) * 64 + sub * 2) * 2;
        float4 v = *(const float4*)pp;
        float s = v.x + v.z, ss = v.y + v.w;
#pragma unroll
        for (int off = 16; off > 0; off >>= 1) {
            s  += __shfl_down(s, off, 32);
            ss += __shfl_down(ss, off, 32);
        }
        if (sub == 0) {
            const float inv = 1.f / (float)(CPG * N_TOK);
            float mean = s * inv;
            float var  = ss * inv - mean * mean;
            stat_s[g][0] = mean;
            stat_s[g][1] = rsqrtf(var + EPS);
        }
        __syncthreads();
    }

    // read 64c x 64n (coalesced along n), normalize, transpose into LDS
#pragma unroll
    for (int r = 0; r < 4; ++r) {
        int idx = tid + (r << 8);
        int crow = idx >> 4, col4 = (idx & 15) << 2;
        int c = c0 + crow;
        int g = c >> 5;
        float ww = norm_w[c] * stat_s[g][1];
        float bb = norm_b[c] - stat_s[g][0] * ww;
        float4 v = *(const float4*)(x + ((size_t)b * C_DIM + c) * N_TOK + n0 + col4);
        Xt[col4 + 0][crow] = f2bf(v.x * ww + bb);
        Xt[col4 + 1][crow] = f2bf(v.y * ww + bb);
        Xt[col4 + 2][crow] = f2bf(v.z * ww + bb);
        Xt[col4 + 3][crow] = f2bf(v.w * ww + bb);
    }
    __syncthreads();

    // write xnT[b][n0+row][c0 + blk*8], 16B per thread
#pragma unroll
    for (int r = 0; r < 2; ++r) {
        int idx = tid + (r << 8);
        int row = idx >> 3, blk = idx & 7;
        *(u16x8v*)(xnT + ((size_t)b * N_TOK + n0 + row) * C_DIM + c0 + blk * 8) =
            *(const u16x8v*)&Xt[row][blk * 8];
    }
}

// ---------------------------------------------------------------------------
// Kernel 2: QKV GEMM, bf16 MFMA, pure-2-DMA, o-tile 256 (512 threads, 8 waves,
// 2 o-frags/wave). xnT re-read drops 12x -> 3x. sidx uniform per block.
__global__ __launch_bounds__(512) void qkv_gemm_kernel(
    const unsigned short* __restrict__ xnT, const unsigned short* __restrict__ wqbf,
    const float* __restrict__ qkv_b, unsigned short* __restrict__ qkvb) {
    __shared__ unsigned short Ws[256][64];  // [o][c] bf16, col-swizzled (32KB)
    __shared__ unsigned short Xs[64][64];   // [n][c] bf16, col-swizzled (8KB)
    const int n0 = blockIdx.x * 64;
    const int o0 = blockIdx.y * 256;        // 0 | 256 | 512  (q | k | v)
    const int b  = blockIdx.z;
    const int tid = threadIdx.x;
    const int lane = tid & 63, w = tid >> 6;
    const int lo = lane & 15, hi = lane >> 4;
    const int tsrow = tid >> 3, tsblk = tid & 7;       // 512-thread staging map
    const int tc16s = (tsblk ^ (tsrow & 7)) * 8;       // swizzled source chunk
    int rcol[2];
#pragma unroll
    for (int c = 0; c < 2; ++c) rcol[c] = (((c * 4 + hi) ^ (lo & 7)) << 3);

    f32x4 acc[2][4] = {};   // acc[f][nb]: o = o0+w*32+f*16+hi*4+i, n = n0+nb*16+lo
    for (int k0 = 0; k0 < C_DIM; k0 += 64) {
        // Ws: 4 DMA issues cover 256 rows (issue i -> rows i*64 + wave-local 8)
#pragma unroll
        for (int i = 0; i < 4; ++i)
            gload16(wqbf + (size_t)(o0 + i * 64 + tsrow) * C_DIM + k0 + tc16s,
                    &Ws[i * 64 + w * 8][0]);
        // Xs: 1 DMA issue covers 64 rows
        gload16(xnT + ((size_t)b * N_TOK + n0 + tsrow) * C_DIM + k0 + tc16s,
                &Xs[w * 8][0]);
        __syncthreads();   // drains DMA
#pragma unroll
        for (int ck = 0; ck < 2; ++ck) {
            bf16x8 aw[2];
#pragma unroll
            for (int f = 0; f < 2; ++f)
                aw[f] = *(const bf16x8*)&Ws[w * 32 + f * 16 + lo][rcol[ck]];
#pragma unroll
            for (int nb = 0; nb < 4; ++nb) {
                bf16x8 xb = *(const bf16x8*)&Xs[nb * 16 + lo][rcol[ck]];
                acc[0][nb] = __builtin_amdgcn_mfma_f32_16x16x32_bf16(aw[0], xb, acc[0][nb], 0, 0, 0);
                acc[1][nb] = __builtin_amdgcn_mfma_f32_16x16x32_bf16(aw[1], xb, acc[1][nb], 0, 0, 0);
            }
        }
        __syncthreads();
    }

    const int sidx = o0 >> 8;           // uniform per block: 0=q, 1=k, 2=v
    const size_t plane = (size_t)N_TOK * HD;
#pragma unroll
    for (int f = 0; f < 2; ++f) {
        const int ob = w * 32 + f * 16;          // o within tile (16-aligned)
        const int head = (ob >> 6) & 3;
        const int od = (ob & 63) + hi * 4;       // d within head (+i)
        float bias[4];
#pragma unroll
        for (int i = 0; i < 4; ++i) bias[i] = qkv_b[o0 + ob + hi * 4 + i];

        if (sidx < 2) {
            const float sc = (sidx == 0) ? QK_SCALE : 1.0f;
            unsigned short* base = qkvb + ((size_t)(sidx * B_DIM + b) * HEADS + head) * plane;
#pragma unroll
            for (int nb = 0; nb < 4; ++nb) {
                int n = n0 + nb * 16 + lo;
                u16x4v o;
#pragma unroll
                for (int i = 0; i < 4; ++i) o[i] = f2bf((acc[f][nb][i] + bias[i]) * sc);
                *(u16x4v*)(base + (size_t)n * HD + od) = o;
            }
        } else {
            unsigned short* base = qkvb + (size_t)2 * B_DIM * HEADS * plane
                                 + ((size_t)b * HEADS + head) * plane;
#pragma unroll
            for (int nb = 0; nb < 4; ++nb) {
                int n = n0 + nb * 16 + lo;
#pragma unroll
                for (int i = 0; i < 4; ++i)
                    base[(size_t)(od + i) * N_TOK + n] = f2bf(acc[f][nb][i] + bias[i]);
            }
        }
    }
}

// ---------------------------------------------------------------------------
// Kernel 3: bf16 MFMA flash attention (round-17 proven: 4 LDS slots, one
// barrier per two tiles; per-tile body identical to round-10/13).
__global__ __launch_bounds__(512, 4) void attn_kernel(const unsigned short* __restrict__ qkvb,
                                                      unsigned short* __restrict__ obuf,
                                                      float* __restrict__ rbuf) {
    const int bh = blockIdx.x & 7;            // b*HEADS + head
    const int ks = (blockIdx.x >> 3) & 3;     // key-split quarter
    const int q0 = (blockIdx.x >> 5) * QBLK;
    const size_t plane = (size_t)N_TOK * HD;
    const unsigned short* Qg  = qkvb + (size_t)bh * plane;
    const unsigned short* Kg  = qkvb + (size_t)(B_DIM * HEADS + bh) * plane;
    const unsigned short* Vtg = qkvb + (size_t)2 * B_DIM * HEADS * plane + (size_t)bh * plane;

    __shared__ unsigned short Ks[4][64][64];  // [slot][perm key row][d] (col-swizzled)
    __shared__ unsigned short Vt[4][64][64];  // [slot][d][key]          (col-swizzled)

    const int tid  = threadIdx.x;
    const int lane = tid & 63;
    const int wid  = tid >> 6;                // 0..7
    const int lo   = lane & 15;
    const int hi   = lane >> 4;

    // Q fragments: frag f covers q = q0 + wid*32 + f*16 + lo, d-chunks c*32+hi*8
    bf16x8 qf[2][2];
#pragma unroll
    for (int f = 0; f < 2; ++f)
#pragma unroll
        for (int c = 0; c < 2; ++c)
            qf[f][c] = *(const bf16x8*)(Qg + (size_t)(q0 + wid * 32 + f * 16 + lo) * HD
                                            + c * 32 + hi * 8);

    const int srow = tid >> 3, sblk = tid & 7;
    const int c16s = (sblk ^ (srow & 7)) * 8;
    const int krow = kperm(srow);
    int rcol[2];
#pragma unroll
    for (int c = 0; c < 2; ++c) rcol[c] = (((c * 4 + hi) ^ (lo & 7)) << 3);

#define STAGE_KV(sloti, kbase)                                                         \
    do {                                                                               \
        gload16(Kg + (size_t)((kbase) + krow) * HD + c16s, &Ks[sloti][wid * 8][0]);    \
        gload16(Vtg + (size_t)srow * N_TOK + (kbase) + c16s, &Vt[sloti][wid * 8][0]);  \
    } while (0)

    const int kt0 = ks * (NKT / KSPLIT), ktE = kt0 + NKT / KSPLIT;   // 16 tiles

    f32x4 acc[2][4] = {};   // acc[f][db][i] = O^T[d=db*16+hi*4+i][q of frag f]
    float m[2] = {-1e30f, -1e30f}, l[2] = {0.f, 0.f};

    // per-tile compute body (identical math to the proven kernel)
    auto compute_tile = [&](int cur) {
        // S^T = K Q^T for BOTH frags; each K fragment read once, used twice.
        f32x4 s4[2][4] = {};
        __builtin_amdgcn_s_setprio(1);
#pragma unroll
        for (int kb = 0; kb < 4; ++kb)
#pragma unroll
            for (int c = 0; c < 2; ++c) {
                bf16x8 kf = *(const bf16x8*)&Ks[cur][kb * 16 + lo][rcol[c]];
                s4[0][kb] = __builtin_amdgcn_mfma_f32_16x16x32_bf16(kf, qf[0][c], s4[0][kb], 0, 0, 0);
                s4[1][kb] = __builtin_amdgcn_mfma_f32_16x16x32_bf16(kf, qf[1][c], s4[1][kb], 0, 0, 0);
            }
        __builtin_amdgcn_s_setprio(0);

        // softmax per frag (lane-local; cross-lane only in rare rescale branch)
        bf16x8 pf[2][2];
#pragma unroll
        for (int f = 0; f < 2; ++f) {
            float r0 = fmaxf(fmaxf(fmaxf(s4[f][0][0], s4[f][0][1]), s4[f][0][2]), s4[f][0][3]);
            float r1 = fmaxf(fmaxf(fmaxf(s4[f][1][0], s4[f][1][1]), s4[f][1][2]), s4[f][1][3]);
            float r2 = fmaxf(fmaxf(fmaxf(s4[f][2][0], s4[f][2][1]), s4[f][2][2]), s4[f][2][3]);
            float r3 = fmaxf(fmaxf(fmaxf(s4[f][3][0], s4[f][3][1]), s4[f][3][2]), s4[f][3][3]);
            float rm = fmaxf(fmaxf(fmaxf(r0, r1), r2), r3);

            // defer-max (T13) with LOCAL max check
            if (__any(rm > m[f] + 8.0f)) {
                float rmx = rm;
                rmx = fmaxf(rmx, __shfl_xor(rmx, 16));
                rmx = fmaxf(rmx, __shfl_xor(rmx, 32));
                const float mn = fmaxf(m[f], rmx);
                const float fi = exp2_fast(m[f] - mn);
                m[f] = mn;
                l[f] *= fi;
#pragma unroll
                for (int db = 0; db < 4; ++db)
#pragma unroll
                    for (int i = 0; i < 4; ++i) acc[f][db][i] *= fi;
            }

            float p[4][4];
            float ps = 0.f;
#pragma unroll
            for (int kb = 0; kb < 4; ++kb)
#pragma unroll
                for (int i = 0; i < 4; ++i) {
                    p[kb][i] = exp2_fast(s4[f][kb][i] - m[f]);
                    ps += p[kb][i];
                }
            l[f] += ps;

            // pack P into PV B-fragment: pf[f][c][j] = p[2c + (j>>2)][j&3]
#pragma unroll
            for (int c = 0; c < 2; ++c)
#pragma unroll
                for (int j = 0; j < 8; ++j) pf[f][c][j] = (__bf16)p[2 * c + (j >> 2)][j & 3];
        }

        // O^T += V^T P^T for BOTH frags; each V fragment read once, used twice.
        __builtin_amdgcn_s_setprio(1);
#pragma unroll
        for (int db = 0; db < 4; ++db)
#pragma unroll
            for (int c = 0; c < 2; ++c) {
                bf16x8 vf = *(const bf16x8*)&Vt[cur][db * 16 + lo][rcol[c]];
                acc[0][db] = __builtin_amdgcn_mfma_f32_16x16x32_bf16(vf, pf[0][c], acc[0][db], 0, 0, 0);
                acc[1][db] = __builtin_amdgcn_mfma_f32_16x16x32_bf16(vf, pf[1][c], acc[1][db], 0, 0, 0);
            }
        __builtin_amdgcn_s_setprio(0);
    };

    // prologue: stage tiles kt0, kt0+1 into slots 0,1
    STAGE_KV(kt0 & 3, kt0 * 64);
    STAGE_KV((kt0 + 1) & 3, (kt0 + 1) * 64);
    __syncthreads();   // drains the DMA (vmcnt 0) + barrier

    for (int kt = kt0; kt < ktE; kt += 2) {
        // stage tiles kt+2, kt+3 into the two slots consumed before last barrier
        if (kt + 2 < ktE) {
            STAGE_KV((kt + 2) & 3, (kt + 2) * 64);
            STAGE_KV((kt + 3) & 3, (kt + 3) * 64);
        }
        compute_tile(kt & 3);
        compute_tile((kt + 1) & 3);
        __syncthreads();   // one barrier per TWO tiles; drains this wave's DMAs
    }
#undef STAGE_KV

    // epilogue per frag: normalized bf16 partial O + log-sum-exp r
#pragma unroll
    for (int f = 0; f < 2; ++f) {
        float l1 = l[f] + __shfl_xor(l[f], 16);
        float lt = l1 + __shfl_xor(l1, 32);
        const float inv = 1.f / lt;
        const int n = q0 + wid * 32 + f * 16 + lo;
        unsigned short* ob = obuf + ((size_t)(ks * 8 + bh) * N_TOK + n) * HD;
#pragma unroll
        for (int db = 0; db < 4; ++db) {
            u16x4v o;
#pragma unroll
            for (int i = 0; i < 4; ++i) o[i] = f2bf(acc[f][db][i] * inv);
            *(u16x4v*)(ob + db * 16 + hi * 4) = o;
        }
        if (hi == 0)
            rbuf[(size_t)(ks * 8 + bh) * N_TOK + n] = m[f] + __builtin_amdgcn_logf(lt);
    }
}

// ---------------------------------------------------------------------------
// Kernel 4: output projection + bias + residual, bf16 MFMA, combine fused into
// Hs staging. o-tile 128 (512 threads, 8 waves x 16 o-rows): obuf/combine
// redundancy halves vs o-tile 64.
__global__ __launch_bounds__(512) void proj_kernel(
    const unsigned short* __restrict__ obuf, const float* __restrict__ rbuf,
    const unsigned short* __restrict__ wpbf, const float* __restrict__ proj_b,
    const float* __restrict__ x, float* __restrict__ out) {
    __shared__ unsigned short Ws[128][64];  // [o][c] bf16, col-swizzled (16KB, DMA)
    __shared__ unsigned short Hs[64][PSB];  // [n][c-within-head], reg-staged
    const int n0 = blockIdx.x * 64;
    const int o0 = blockIdx.y * 128;
    const int b  = blockIdx.z;
    const int tid = threadIdx.x;
    const int lane = tid & 63, w = tid >> 6;
    const int lo = lane & 15, hi = lane >> 4;
    const int tsrow = tid >> 3, tsblk = tid & 7;
    const int tc16s = (tsblk ^ (tsrow & 7)) * 8;
    int rcol[2];
#pragma unroll
    for (int c = 0; c < 2; ++c) rcol[c] = (((c * 4 + hi) ^ (lo & 7)) << 3);

    f32x4 acc[4] = {};      // o = o0 + w*16 + hi*4 + i, n = n0 + nb*16 + lo
    for (int k0 = 0; k0 < C_DIM; k0 += 64) {
        // Ws via DMA: 2 issues cover 128 rows
#pragma unroll
        for (int i = 0; i < 2; ++i)
            gload16(wpbf + (size_t)(o0 + i * 64 + tsrow) * C_DIM + k0 + tc16s,
                    &Ws[i * 64 + w * 8][0]);
        // stage h[n][k0..k0+64): head = k0>>6; combine the 4 K-split partials
        // 512 threads cover 64 rows x 8 chunks in ONE pass.
        {
            const int head = k0 >> 6;
            const int bh = b * HEADS + head;
            int row = tsrow, blk = tsblk;
            int n = n0 + row;
            float rr[KSPLIT], M = -1e30f;
#pragma unroll
            for (int k = 0; k < KSPLIT; ++k) {
                rr[k] = rbuf[(size_t)(k * 8 + bh) * N_TOK + n];
                M = fmaxf(M, rr[k]);
            }
            float wk[KSPLIT], tot = 0.f;
#pragma unroll
            for (int k = 0; k < KSPLIT; ++k) { wk[k] = exp2_fast(rr[k] - M); tot += wk[k]; }
            const float inv = 1.f / tot;
            float a[8] = {};
#pragma unroll
            for (int k = 0; k < KSPLIT; ++k) {
                u16x8v v = *(const u16x8v*)(obuf
                    + ((size_t)(k * 8 + bh) * N_TOK + n) * HD + blk * 8);
#pragma unroll
                for (int j = 0; j < 8; ++j) a[j] += wk[k] * bf2f(v[j]);
            }
            u16x8v o;
#pragma unroll
            for (int j = 0; j < 8; ++j) o[j] = f2bf(a[j] * inv);
            *(u16x8v*)&Hs[row][blk * 8] = o;
        }
        __syncthreads();   // drains DMA (vmcnt) + ds_writes (lgkm)
#pragma unroll
        for (int ck = 0; ck < 2; ++ck) {
            bf16x8 aw = *(const bf16x8*)&Ws[w * 16 + lo][rcol[ck]];
#pragma unroll
            for (int nb = 0; nb < 4; ++nb)
                acc[nb] = __builtin_amdgcn_mfma_f32_16x16x32_bf16(
                    aw, *(const bf16x8*)&Hs[nb * 16 + lo][ck * 32 + hi * 8], acc[nb], 0, 0, 0);
        }
        __syncthreads();
    }

#pragma unroll
    for (int nb = 0; nb < 4; ++nb) {
#pragma unroll
        for (int i = 0; i < 4; ++i) {
            int o = o0 + w * 16 + hi * 4 + i;
            size_t addr = ((size_t)b * C_DIM + o) * N_TOK + n0 + nb * 16 + lo;
            out[addr] = acc[nb][i] + proj_b[o] + x[addr];
        }
    }
}

// ---------------------------------------------------------------------------
extern "C" void kernel_launch(void* const* d_in, const int* in_sizes, int n_in,
                              void* d_out, int out_size, void* d_ws, size_t ws_size,
                              hipStream_t stream) {
    const float* x      = (const float*)d_in[0];
    const float* norm_w = (const float*)d_in[1];
    const float* norm_b = (const float*)d_in[2];
    const float* qkv_w  = (const float*)d_in[3];
    const float* qkv_b  = (const float*)d_in[4];
    const float* proj_w = (const float*)d_in[5];
    const float* proj_b = (const float*)d_in[6];
    float* out = (float*)d_out;

    // ws: partials f32[2048] (8KB) | wbf u16[262144] (512KB) | xnT bf16 (4.2MB)
    //   | qkvb bf16 (12.6MB) | obuf bf16 [4][8][N][HD] (16.8MB)
    //   | rbuf f32 [4][8][N] (512KB)  ~= 34.6MB
    float* partials = (float*)d_ws;
    unsigned short* wbf = (unsigned short*)(partials + 2048);
    unsigned short* xnT = wbf + (NQKVW + NPROJW);
    unsigned short* qkvb = xnT + (size_t)B_DIM * N_TOK * C_DIM;
    unsigned short* obuf = qkvb + (size_t)3 * B_DIM * HEADS * N_TOK * HD;
    float* rbuf = (float*)(obuf + (size_t)KSPLIT * B_DIM * HEADS * N_TOK * HD);
    const unsigned short* wqbf = wbf;
    const unsigned short* wpbf = wbf + NQKVW;

    gn_part_kernel<<<B_DIM * GROUPS * 64, 256, 0, stream>>>(x, qkv_w, proj_w, partials, wbf);
    xnorm_kernel<<<dim3(N_TOK / 64, C_DIM / 64, B_DIM), 256, 0, stream>>>(
        x, partials, norm_w, norm_b, xnT);
    qkv_gemm_kernel<<<dim3(N_TOK / 64, 3, B_DIM), 512, 0, stream>>>(
        xnT, wqbf, qkv_b, qkvb);
    attn_kernel<<<(N_TOK / QBLK) * B_DIM * HEADS * KSPLIT, 512, 0, stream>>>(qkvb, obuf, rbuf);
    proj_kernel<<<dim3(N_TOK / 64, 2, B_DIM), 512, 0, stream>>>(
        obuf, rbuf, wpbf, proj_b, x, out);
}

// Round 20
// 76.545 us; speedup vs baseline: 1.2763x; 1.0184x over previous
//
#include <hip/hip_runtime.h>
#include <math.h>

#define B_DIM 2
#define C_DIM 256
#define N_TOK 4096      // 16*16*16
#define HEADS 4
#define HD 64
#define GROUPS 8
#define CPG (C_DIM / GROUPS)   // 32
#define EPS 1e-5f
#define PSB 72          // padded bf16 LDS row stride (reg-staged tiles)
#define QK_SCALE 0.180336880f  // 0.125 * log2(e), folded into Q
#define KSPLIT 4
#define NKT (N_TOK / 64)       // 64 key tiles total
#define QBLK 256               // queries per attention block (8 waves x 2 frags x 16 q)
#define NQKVW (3 * C_DIM * C_DIM)   // 196608 qkv_w elems
#define NPROJW (C_DIM * C_DIM)      // 65536 proj_w elems

typedef __bf16 bf16x8 __attribute__((ext_vector_type(8)));
typedef float  f32x4  __attribute__((ext_vector_type(4)));
typedef unsigned short u16x4v __attribute__((ext_vector_type(4)));
typedef unsigned short u16x8v __attribute__((ext_vector_type(8)));

__device__ __forceinline__ unsigned short f2bf(float f) {
    return __builtin_bit_cast(unsigned short, (__bf16)f);
}
__device__ __forceinline__ float bf2f(unsigned short u) {
    return (float)__builtin_bit_cast(__bf16, u);
}
// raw v_exp_f32 (2^x); inputs bounded so no OCML fixup needed
__device__ __forceinline__ float exp2_fast(float x) { return __builtin_amdgcn_exp2f(x); }

// async global->LDS, 16B per lane, wave-uniform LDS base (linear dest)
__device__ __forceinline__ void gload16(const unsigned short* g, unsigned short* l) {
    __builtin_amdgcn_global_load_lds(
        (const __attribute__((address_space(1))) unsigned int*)g,
        (__attribute__((address_space(3))) unsigned int*)l, 16, 0, 0);
}

// K-staging row permutation: [b5 b4 b3 b2 b1 b0] -> [b5 b3 b2 b4 b1 b0].
// Makes the S^T output registers exactly the PV B-fragment.
__device__ __forceinline__ int kperm(int r) {
    return (r & 0x23) | ((r & 0x0C) << 1) | ((r & 0x10) >> 2);
}

// ---------------------------------------------------------------------------
// Kernel 1: GroupNorm partial sums (1024 blocks) + weight f32->bf16 convert
// tail (262144 = 1024*256 elems, one per thread, coalesced).
__global__ __launch_bounds__(256) void gn_part_kernel(const float* __restrict__ x,
                                                      const float* __restrict__ qkv_w,
                                                      const float* __restrict__ proj_w,
                                                      float* __restrict__ partials,
                                                      unsigned short* __restrict__ wbf) {
    const int bg = blockIdx.x >> 6, ch = blockIdx.x & 63;
    const float4* p = (const float4*)(x + (size_t)bg * CPG * N_TOK) + ch * 512;
    float s = 0.f, ss = 0.f;
#pragma unroll
    for (int r = 0; r < 2; ++r) {
        float4 v = p[threadIdx.x + (r << 8)];
        s  += v.x + v.y + v.z + v.w;
        ss += v.x * v.x + v.y * v.y + v.z * v.z + v.w * v.w;
    }
#pragma unroll
    for (int off = 32; off > 0; off >>= 1) {
        s  += __shfl_down(s, off);
        ss += __shfl_down(ss, off);
    }
    __shared__ float ls[4], lss[4];
    const int lane = threadIdx.x & 63, wid = threadIdx.x >> 6;
    if (lane == 0) { ls[wid] = s; lss[wid] = ss; }

    // weight convert tail (no sync needed; independent outputs)
    const int widx = blockIdx.x * 256 + threadIdx.x;
    float wv = (widx < NQKVW) ? qkv_w[widx] : proj_w[widx - NQKVW];
    wbf[widx] = f2bf(wv);

    __syncthreads();
    if (threadIdx.x == 0) {
        partials[blockIdx.x * 2 + 0] = ls[0] + ls[1] + ls[2] + ls[3];
        partials[blockIdx.x * 2 + 1] = lss[0] + lss[1] + lss[2] + lss[3];
    }
}

// ---------------------------------------------------------------------------
// Kernel 1b: GroupNorm finalize + apply + transpose -> xnT bf16 [b][n][c].
__global__ __launch_bounds__(256) void xnorm_kernel(const float* __restrict__ x,
                                                    const float* __restrict__ partials,
                                                    const float* __restrict__ norm_w,
                                                    const float* __restrict__ norm_b,
                                                    unsigned short* __restrict__ xnT) {
    __shared__ unsigned short Xt[64][PSB];  // [n][c] bf16
    __shared__ float stat_s[GROUPS][2];
    const int n0 = blockIdx.x * 64;
    const int c0 = blockIdx.y * 64;
    const int b  = blockIdx.z;
    const int tid = threadIdx.x;

    // finalize GroupNorm stats from partials
    {
        const int g = tid >> 5, sub = tid & 31;
        const float* pp = partials + (((size_t)b * GROUPS + g) * 64 + sub * 2) * 2;
        float4 v = *(const float4*)pp;
        float s = v.x + v.z, ss = v.y + v.w;
#pragma unroll
        for (int off = 16; off > 0; off >>= 1) {
            s  += __shfl_down(s, off, 32);
            ss += __shfl_down(ss, off, 32);
        }
        if (sub == 0) {
            const float inv = 1.f / (float)(CPG * N_TOK);
            float mean = s * inv;
            float var  = ss * inv - mean * mean;
            stat_s[g][0] = mean;
            stat_s[g][1] = rsqrtf(var + EPS);
        }
        __syncthreads();
    }

    // read 64c x 64n (coalesced along n), normalize, transpose into LDS
#pragma unroll
    for (int r = 0; r < 4; ++r) {
        int idx = tid + (r << 8);
        int crow = idx >> 4, col4 = (idx & 15) << 2;
        int c = c0 + crow;
        int g = c >> 5;
        float ww = norm_w[c] * stat_s[g][1];
        float bb = norm_b[c] - stat_s[g][0] * ww;
        float4 v = *(const float4*)(x + ((size_t)b * C_DIM + c) * N_TOK + n0 + col4);
        Xt[col4 + 0][crow] = f2bf(v.x * ww + bb);
        Xt[col4 + 1][crow] = f2bf(v.y * ww + bb);
        Xt[col4 + 2][crow] = f2bf(v.z * ww + bb);
        Xt[col4 + 3][crow] = f2bf(v.w * ww + bb);
    }
    __syncthreads();

    // write xnT[b][n0+row][c0 + blk*8], 16B per thread
#pragma unroll
    for (int r = 0; r < 2; ++r) {
        int idx = tid + (r << 8);
        int row = idx >> 3, blk = idx & 7;
        *(u16x8v*)(xnT + ((size_t)b * N_TOK + n0 + row) * C_DIM + c0 + blk * 8) =
            *(const u16x8v*)&Xt[row][blk * 8];
    }
}

// ---------------------------------------------------------------------------
// Kernel 2: QKV GEMM, bf16 MFMA, pure-2-DMA, o-tile 256 (512 threads, 8 waves,
// 2 o-frags/wave). Epilogue now LDS-transposes the output tile so ALL global
// stores are coalesced 16B (q/k were 8B at 128B stride, v was 2B scalars).
union QkvShared {
    struct { unsigned short Ws[256][64]; unsigned short Xs[64][64]; } g;  // 40KB
    unsigned short T[64][264];   // q/k epilogue: [n][o], stride 264 (16B-aligned rows)
    unsigned short V[256][72];   // v epilogue:  [o][n], stride 72 (16B-aligned rows)
};
__global__ __launch_bounds__(512) void qkv_gemm_kernel(
    const unsigned short* __restrict__ xnT, const unsigned short* __restrict__ wqbf,
    const float* __restrict__ qkv_b, unsigned short* __restrict__ qkvb) {
    __shared__ QkvShared sh;
    const int n0 = blockIdx.x * 64;
    const int o0 = blockIdx.y * 256;        // 0 | 256 | 512  (q | k | v)
    const int b  = blockIdx.z;
    const int tid = threadIdx.x;
    const int lane = tid & 63, w = tid >> 6;
    const int lo = lane & 15, hi = lane >> 4;
    const int tsrow = tid >> 3, tsblk = tid & 7;       // 512-thread staging map
    const int tc16s = (tsblk ^ (tsrow & 7)) * 8;       // swizzled source chunk
    int rcol[2];
#pragma unroll
    for (int c = 0; c < 2; ++c) rcol[c] = (((c * 4 + hi) ^ (lo & 7)) << 3);

    f32x4 acc[2][4] = {};   // acc[f][nb]: o = o0+w*32+f*16+hi*4+i, n = n0+nb*16+lo
    for (int k0 = 0; k0 < C_DIM; k0 += 64) {
        // Ws: 4 DMA issues cover 256 rows (issue i -> rows i*64 + wave-local 8)
#pragma unroll
        for (int i = 0; i < 4; ++i)
            gload16(wqbf + (size_t)(o0 + i * 64 + tsrow) * C_DIM + k0 + tc16s,
                    &sh.g.Ws[i * 64 + w * 8][0]);
        // Xs: 1 DMA issue covers 64 rows
        gload16(xnT + ((size_t)b * N_TOK + n0 + tsrow) * C_DIM + k0 + tc16s,
                &sh.g.Xs[w * 8][0]);
        __syncthreads();   // drains DMA
#pragma unroll
        for (int ck = 0; ck < 2; ++ck) {
            bf16x8 aw[2];
#pragma unroll
            for (int f = 0; f < 2; ++f)
                aw[f] = *(const bf16x8*)&sh.g.Ws[w * 32 + f * 16 + lo][rcol[ck]];
#pragma unroll
            for (int nb = 0; nb < 4; ++nb) {
                bf16x8 xb = *(const bf16x8*)&sh.g.Xs[nb * 16 + lo][rcol[ck]];
                acc[0][nb] = __builtin_amdgcn_mfma_f32_16x16x32_bf16(aw[0], xb, acc[0][nb], 0, 0, 0);
                acc[1][nb] = __builtin_amdgcn_mfma_f32_16x16x32_bf16(aw[1], xb, acc[1][nb], 0, 0, 0);
            }
        }
        __syncthreads();
    }
    // after the final barrier every wave is done reading g.Ws/g.Xs: LDS is free

    const int sidx = o0 >> 8;           // uniform per block: 0=q, 1=k, 2=v
    const size_t plane = (size_t)N_TOK * HD;

    if (sidx < 2) {
        const float sc = (sidx == 0) ? QK_SCALE : 1.0f;
        // stage [n][o]: row stride 264 elems (528B); 16 lanes/bank-pair = 2-way (free)
#pragma unroll
        for (int f = 0; f < 2; ++f) {
            const int ob = w * 32 + f * 16 + hi * 4;
            float bias[4];
#pragma unroll
            for (int i = 0; i < 4; ++i) bias[i] = qkv_b[o0 + ob + i];
#pragma unroll
            for (int nb = 0; nb < 4; ++nb) {
                u16x4v t;
#pragma unroll
                for (int i = 0; i < 4; ++i) t[i] = f2bf((acc[f][nb][i] + bias[i]) * sc);
                *(u16x4v*)&sh.T[nb * 16 + lo][ob] = t;
            }
        }
        __syncthreads();
        // coalesced 16B global stores: 2048 chunks / 512 threads = 4 each
#pragma unroll
        for (int r = 0; r < 4; ++r) {
            int idx = r * 512 + tid;
            int blk = idx & 7, n = (idx >> 3) & 63, h = idx >> 9;
            unsigned short* base = qkvb + ((size_t)(sidx * B_DIM + b) * HEADS + h) * plane;
            *(u16x8v*)(base + (size_t)(n0 + n) * HD + blk * 8) =
                *(const u16x8v*)&sh.T[n][h * 64 + blk * 8];
        }
    } else {
        // v: stage [o][n]: row stride 72 elems (144B, 16B-aligned)
#pragma unroll
        for (int f = 0; f < 2; ++f) {
            const int ob = w * 32 + f * 16 + hi * 4;
            float bias[4];
#pragma unroll
            for (int i = 0; i < 4; ++i) bias[i] = qkv_b[o0 + ob + i];
#pragma unroll
            for (int nb = 0; nb < 4; ++nb) {
                int n = nb * 16 + lo;
#pragma unroll
                for (int i = 0; i < 4; ++i)
                    sh.V[ob + i][n] = f2bf(acc[f][nb][i] + bias[i]);
            }
        }
        __syncthreads();
        // coalesced 16B global stores: v[d][n], n contiguous
        unsigned short* vbase = qkvb + (size_t)2 * B_DIM * HEADS * plane
                              + ((size_t)b * HEADS) * plane;
#pragma unroll
        for (int r = 0; r < 4; ++r) {
            int idx = r * 512 + tid;
            int o = idx >> 3, blk = idx & 7;
            int h = o >> 6, d = o & 63;
            *(u16x8v*)(vbase + (size_t)h * plane + (size_t)d * N_TOK + n0 + blk * 8) =
                *(const u16x8v*)&sh.V[o][blk * 8];
        }
    }
}

// ---------------------------------------------------------------------------
// Kernel 3: bf16 MFMA flash attention (round-17 proven: 4 LDS slots, one
// barrier per two tiles; per-tile body identical to round-10/13).
__global__ __launch_bounds__(512, 4) void attn_kernel(const unsigned short* __restrict__ qkvb,
                                                      unsigned short* __restrict__ obuf,
                                                      float* __restrict__ rbuf) {
    const int bh = blockIdx.x & 7;            // b*HEADS + head
    const int ks = (blockIdx.x >> 3) & 3;     // key-split quarter
    const int q0 = (blockIdx.x >> 5) * QBLK;
    const size_t plane = (size_t)N_TOK * HD;
    const unsigned short* Qg  = qkvb + (size_t)bh * plane;
    const unsigned short* Kg  = qkvb + (size_t)(B_DIM * HEADS + bh) * plane;
    const unsigned short* Vtg = qkvb + (size_t)2 * B_DIM * HEADS * plane + (size_t)bh * plane;

    __shared__ unsigned short Ks[4][64][64];  // [slot][perm key row][d] (col-swizzled)
    __shared__ unsigned short Vt[4][64][64];  // [slot][d][key]          (col-swizzled)

    const int tid  = threadIdx.x;
    const int lane = tid & 63;
    const int wid  = tid >> 6;                // 0..7
    const int lo   = lane & 15;
    const int hi   = lane >> 4;

    // Q fragments: frag f covers q = q0 + wid*32 + f*16 + lo, d-chunks c*32+hi*8
    bf16x8 qf[2][2];
#pragma unroll
    for (int f = 0; f < 2; ++f)
#pragma unroll
        for (int c = 0; c < 2; ++c)
            qf[f][c] = *(const bf16x8*)(Qg + (size_t)(q0 + wid * 32 + f * 16 + lo) * HD
                                            + c * 32 + hi * 8);

    const int srow = tid >> 3, sblk = tid & 7;
    const int c16s = (sblk ^ (srow & 7)) * 8;
    const int krow = kperm(srow);
    int rcol[2];
#pragma unroll
    for (int c = 0; c < 2; ++c) rcol[c] = (((c * 4 + hi) ^ (lo & 7)) << 3);

#define STAGE_KV(sloti, kbase)                                                         \
    do {                                                                               \
        gload16(Kg + (size_t)((kbase) + krow) * HD + c16s, &Ks[sloti][wid * 8][0]);    \
        gload16(Vtg + (size_t)srow * N_TOK + (kbase) + c16s, &Vt[sloti][wid * 8][0]);  \
    } while (0)

    const int kt0 = ks * (NKT / KSPLIT), ktE = kt0 + NKT / KSPLIT;   // 16 tiles

    f32x4 acc[2][4] = {};   // acc[f][db][i] = O^T[d=db*16+hi*4+i][q of frag f]
    float m[2] = {-1e30f, -1e30f}, l[2] = {0.f, 0.f};

    // per-tile compute body (identical math to the proven kernel)
    auto compute_tile = [&](int cur) {
        // S^T = K Q^T for BOTH frags; each K fragment read once, used twice.
        f32x4 s4[2][4] = {};
        __builtin_amdgcn_s_setprio(1);
#pragma unroll
        for (int kb = 0; kb < 4; ++kb)
#pragma unroll
            for (int c = 0; c < 2; ++c) {
                bf16x8 kf = *(const bf16x8*)&Ks[cur][kb * 16 + lo][rcol[c]];
                s4[0][kb] = __builtin_amdgcn_mfma_f32_16x16x32_bf16(kf, qf[0][c], s4[0][kb], 0, 0, 0);
                s4[1][kb] = __builtin_amdgcn_mfma_f32_16x16x32_bf16(kf, qf[1][c], s4[1][kb], 0, 0, 0);
            }
        __builtin_amdgcn_s_setprio(0);

        // softmax per frag (lane-local; cross-lane only in rare rescale branch)
        bf16x8 pf[2][2];
#pragma unroll
        for (int f = 0; f < 2; ++f) {
            float r0 = fmaxf(fmaxf(fmaxf(s4[f][0][0], s4[f][0][1]), s4[f][0][2]), s4[f][0][3]);
            float r1 = fmaxf(fmaxf(fmaxf(s4[f][1][0], s4[f][1][1]), s4[f][1][2]), s4[f][1][3]);
            float r2 = fmaxf(fmaxf(fmaxf(s4[f][2][0], s4[f][2][1]), s4[f][2][2]), s4[f][2][3]);
            float r3 = fmaxf(fmaxf(fmaxf(s4[f][3][0], s4[f][3][1]), s4[f][3][2]), s4[f][3][3]);
            float rm = fmaxf(fmaxf(fmaxf(r0, r1), r2), r3);

            // defer-max (T13) with LOCAL max check
            if (__any(rm > m[f] + 8.0f)) {
                float rmx = rm;
                rmx = fmaxf(rmx, __shfl_xor(rmx, 16));
                rmx = fmaxf(rmx, __shfl_xor(rmx, 32));
                const float mn = fmaxf(m[f], rmx);
                const float fi = exp2_fast(m[f] - mn);
                m[f] = mn;
                l[f] *= fi;
#pragma unroll
                for (int db = 0; db < 4; ++db)
#pragma unroll
                    for (int i = 0; i < 4; ++i) acc[f][db][i] *= fi;
            }

            float p[4][4];
            float ps = 0.f;
#pragma unroll
            for (int kb = 0; kb < 4; ++kb)
#pragma unroll
                for (int i = 0; i < 4; ++i) {
                    p[kb][i] = exp2_fast(s4[f][kb][i] - m[f]);
                    ps += p[kb][i];
                }
            l[f] += ps;

            // pack P into PV B-fragment: pf[f][c][j] = p[2c + (j>>2)][j&3]
#pragma unroll
            for (int c = 0; c < 2; ++c)
#pragma unroll
                for (int j = 0; j < 8; ++j) pf[f][c][j] = (__bf16)p[2 * c + (j >> 2)][j & 3];
        }

        // O^T += V^T P^T for BOTH frags; each V fragment read once, used twice.
        __builtin_amdgcn_s_setprio(1);
#pragma unroll
        for (int db = 0; db < 4; ++db)
#pragma unroll
            for (int c = 0; c < 2; ++c) {
                bf16x8 vf = *(const bf16x8*)&Vt[cur][db * 16 + lo][rcol[c]];
                acc[0][db] = __builtin_amdgcn_mfma_f32_16x16x32_bf16(vf, pf[0][c], acc[0][db], 0, 0, 0);
                acc[1][db] = __builtin_amdgcn_mfma_f32_16x16x32_bf16(vf, pf[1][c], acc[1][db], 0, 0, 0);
            }
        __builtin_amdgcn_s_setprio(0);
    };

    // prologue: stage tiles kt0, kt0+1 into slots 0,1
    STAGE_KV(kt0 & 3, kt0 * 64);
    STAGE_KV((kt0 + 1) & 3, (kt0 + 1) * 64);
    __syncthreads();   // drains the DMA (vmcnt 0) + barrier

    for (int kt = kt0; kt < ktE; kt += 2) {
        // stage tiles kt+2, kt+3 into the two slots consumed before last barrier
        if (kt + 2 < ktE) {
            STAGE_KV((kt + 2) & 3, (kt + 2) * 64);
            STAGE_KV((kt + 3) & 3, (kt + 3) * 64);
        }
        compute_tile(kt & 3);
        compute_tile((kt + 1) & 3);
        __syncthreads();   // one barrier per TWO tiles; drains this wave's DMAs
    }
#undef STAGE_KV

    // epilogue per frag: normalized bf16 partial O + log-sum-exp r
#pragma unroll
    for (int f = 0; f < 2; ++f) {
        float l1 = l[f] + __shfl_xor(l[f], 16);
        float lt = l1 + __shfl_xor(l1, 32);
        const float inv = 1.f / lt;
        const int n = q0 + wid * 32 + f * 16 + lo;
        unsigned short* ob = obuf + ((size_t)(ks * 8 + bh) * N_TOK + n) * HD;
#pragma unroll
        for (int db = 0; db < 4; ++db) {
            u16x4v o;
#pragma unroll
            for (int i = 0; i < 4; ++i) o[i] = f2bf(acc[f][db][i] * inv);
            *(u16x4v*)(ob + db * 16 + hi * 4) = o;
        }
        if (hi == 0)
            rbuf[(size_t)(ks * 8 + bh) * N_TOK + n] = m[f] + __builtin_amdgcn_logf(lt);
    }
}

// ---------------------------------------------------------------------------
// Kernel 4: output projection + bias + residual, bf16 MFMA, combine fused into
// Hs staging. o-tile 128 (512 threads, 8 waves x 16 o-rows).
__global__ __launch_bounds__(512) void proj_kernel(
    const unsigned short* __restrict__ obuf, const float* __restrict__ rbuf,
    const unsigned short* __restrict__ wpbf, const float* __restrict__ proj_b,
    const float* __restrict__ x, float* __restrict__ out) {
    __shared__ unsigned short Ws[128][64];  // [o][c] bf16, col-swizzled (16KB, DMA)
    __shared__ unsigned short Hs[64][PSB];  // [n][c-within-head], reg-staged
    const int n0 = blockIdx.x * 64;
    const int o0 = blockIdx.y * 128;
    const int b  = blockIdx.z;
    const int tid = threadIdx.x;
    const int lane = tid & 63, w = tid >> 6;
    const int lo = lane & 15, hi = lane >> 4;
    const int tsrow = tid >> 3, tsblk = tid & 7;
    const int tc16s = (tsblk ^ (tsrow & 7)) * 8;
    int rcol[2];
#pragma unroll
    for (int c = 0; c < 2; ++c) rcol[c] = (((c * 4 + hi) ^ (lo & 7)) << 3);

    f32x4 acc[4] = {};      // o = o0 + w*16 + hi*4 + i, n = n0 + nb*16 + lo
    for (int k0 = 0; k0 < C_DIM; k0 += 64) {
        // Ws via DMA: 2 issues cover 128 rows
#pragma unroll
        for (int i = 0; i < 2; ++i)
            gload16(wpbf + (size_t)(o0 + i * 64 + tsrow) * C_DIM + k0 + tc16s,
                    &Ws[i * 64 + w * 8][0]);
        // stage h[n][k0..k0+64): head = k0>>6; combine the 4 K-split partials
        // 512 threads cover 64 rows x 8 chunks in ONE pass.
        {
            const int head = k0 >> 6;
            const int bh = b * HEADS + head;
            int row = tsrow, blk = tsblk;
            int n = n0 + row;
            float rr[KSPLIT], M = -1e30f;
#pragma unroll
            for (int k = 0; k < KSPLIT; ++k) {
                rr[k] = rbuf[(size_t)(k * 8 + bh) * N_TOK + n];
                M = fmaxf(M, rr[k]);
            }
            float wk[KSPLIT], tot = 0.f;
#pragma unroll
            for (int k = 0; k < KSPLIT; ++k) { wk[k] = exp2_fast(rr[k] - M); tot += wk[k]; }
            const float inv = 1.f / tot;
            float a[8] = {};
#pragma unroll
            for (int k = 0; k < KSPLIT; ++k) {
                u16x8v v = *(const u16x8v*)(obuf
                    + ((size_t)(k * 8 + bh) * N_TOK + n) * HD + blk * 8);
#pragma unroll
                for (int j = 0; j < 8; ++j) a[j] += wk[k] * bf2f(v[j]);
            }
            u16x8v o;
#pragma unroll
            for (int j = 0; j < 8; ++j) o[j] = f2bf(a[j] * inv);
            *(u16x8v*)&Hs[row][blk * 8] = o;
        }
        __syncthreads();   // drains DMA (vmcnt) + ds_writes (lgkm)
#pragma unroll
        for (int ck = 0; ck < 2; ++ck) {
            bf16x8 aw = *(const bf16x8*)&Ws[w * 16 + lo][rcol[ck]];
#pragma unroll
            for (int nb = 0; nb < 4; ++nb)
                acc[nb] = __builtin_amdgcn_mfma_f32_16x16x32_bf16(
                    aw, *(const bf16x8*)&Hs[nb * 16 + lo][ck * 32 + hi * 8], acc[nb], 0, 0, 0);
        }
        __syncthreads();
    }

#pragma unroll
    for (int nb = 0; nb < 4; ++nb) {
#pragma unroll
        for (int i = 0; i < 4; ++i) {
            int o = o0 + w * 16 + hi * 4 + i;
            size_t addr = ((size_t)b * C_DIM + o) * N_TOK + n0 + nb * 16 + lo;
            out[addr] = acc[nb][i] + proj_b[o] + x[addr];
        }
    }
}

// ---------------------------------------------------------------------------
extern "C" void kernel_launch(void* const* d_in, const int* in_sizes, int n_in,
                              void* d_out, int out_size, void* d_ws, size_t ws_size,
                              hipStream_t stream) {
    const float* x      = (const float*)d_in[0];
    const float* norm_w = (const float*)d_in[1];
    const float* norm_b = (const float*)d_in[2];
    const float* qkv_w  = (const float*)d_in[3];
    const float* qkv_b  = (const float*)d_in[4];
    const float* proj_w = (const float*)d_in[5];
    const float* proj_b = (const float*)d_in[6];
    float* out = (float*)d_out;

    // ws: partials f32[2048] (8KB) | wbf u16[262144] (512KB) | xnT bf16 (4.2MB)
    //   | qkvb bf16 (12.6MB) | obuf bf16 [4][8][N][HD] (16.8MB)
    //   | rbuf f32 [4][8][N] (512KB)  ~= 34.6MB
    float* partials = (float*)d_ws;
    unsigned short* wbf = (unsigned short*)(partials + 2048);
    unsigned short* xnT = wbf + (NQKVW + NPROJW);
    unsigned short* qkvb = xnT + (size_t)B_DIM * N_TOK * C_DIM;
    unsigned short* obuf = qkvb + (size_t)3 * B_DIM * HEADS * N_TOK * HD;
    float* rbuf = (float*)(obuf + (size_t)KSPLIT * B_DIM * HEADS * N_TOK * HD);
    const unsigned short* wqbf = wbf;
    const unsigned short* wpbf = wbf + NQKVW;

    gn_part_kernel<<<B_DIM * GROUPS * 64, 256, 0, stream>>>(x, qkv_w, proj_w, partials, wbf);
    xnorm_kernel<<<dim3(N_TOK / 64, C_DIM / 64, B_DIM), 256, 0, stream>>>(
        x, partials, norm_w, norm_b, xnT);
    qkv_gemm_kernel<<<dim3(N_TOK / 64, 3, B_DIM), 512, 0, stream>>>(
        xnT, wqbf, qkv_b, qkvb);
    attn_kernel<<<(N_TOK / QBLK) * B_DIM * HEADS * KSPLIT, 512, 0, stream>>>(qkvb, obuf, rbuf);
    proj_kernel<<<dim3(N_TOK / 64, 2, B_DIM), 512, 0, stream>>>(
        obuf, rbuf, wpbf, proj_b, x, out);
}